// Round 1
// baseline (1255.735 us; speedup 1.0000x reference)
//
#include <hip/hip_runtime.h>
#include <math.h>

#define TINYF 1.17549435e-38f
#define GMAX 16.0f   // hard upper bound on gumbel (15.9424) + slack
#define QCAP2 4096

typedef __attribute__((ext_vector_type(8))) short bf16x8;
typedef __attribute__((ext_vector_type(4))) float f32x4;

// ---------------- threefry2x32, key = (0, 42) ----------------
__device__ __forceinline__ unsigned rotl32(unsigned x, int r) {
  return (x << r) | (x >> (32 - r));
}

__device__ __forceinline__ unsigned tf2x32_xor(unsigned x0, unsigned x1) {
  const unsigned k0 = 0u, k1 = 42u, k2 = 0x1BD11BF0u;  // 0x1BD11BDA ^ 0 ^ 42
  x0 += k0; x1 += k1;
#define TFR(r) { x0 += x1; x1 = rotl32(x1, r); x1 ^= x0; }
  TFR(13) TFR(15) TFR(26) TFR(6)
  x0 += k1; x1 += k2 + 1u;
  TFR(17) TFR(29) TFR(16) TFR(24)
  x0 += k2; x1 += k0 + 2u;
  TFR(13) TFR(15) TFR(26) TFR(6)
  x0 += k0; x1 += k1 + 3u;
  TFR(17) TFR(29) TFR(16) TFR(24)
  x0 += k1; x1 += k2 + 4u;
  TFR(13) TFR(15) TFR(26) TFR(6)
  x0 += k2; x1 += k0 + 5u;
#undef TFR
  return x0 ^ x1;
}

__device__ __forceinline__ float gumbel_from_bits(unsigned bits) {
  float f = __uint_as_float((bits >> 9) | 0x3f800000u) - 1.0f;
  float u = fmaxf(f, TINYF);
  return -logf(-logf(u));
}

// order-preserving float->uint (monotone)
__device__ __forceinline__ unsigned ordf(float v) {
  unsigned b = __float_as_uint(v);
  return (b & 0x80000000u) ? ~b : (b | 0x80000000u);
}
__device__ __forceinline__ float unordf(unsigned u) {
  unsigned b = (u & 0x80000000u) ? (u & 0x7FFFFFFFu) : ~u;
  return __uint_as_float(b);
}

// fp32 -> bf16 RNE (bit trick)
__device__ __forceinline__ unsigned short f2bf(float f) {
  unsigned u = __float_as_uint(f);
  unsigned r = u + 0x7FFFu + ((u >> 16) & 1u);
  return (unsigned short)(r >> 16);
}
__device__ __forceinline__ unsigned pk2(float a, float b) {
  return (unsigned)f2bf(a) | ((unsigned)f2bf(b) << 16);
}
// LDS XOR swizzle for 256B-row tile (breaks 32-way ds_read_b128 conflict)
__device__ __forceinline__ int bswz(int b) { return b ^ (((b >> 8) & 7) << 4); }

// ---------------- h = x @ W + b (f64 accumulate) + workspace init ----------
__global__ void k_hraw(const float* __restrict__ x, const float* __restrict__ W,
                       const float* __restrict__ b, float* __restrict__ hraw,
                       unsigned long long* __restrict__ rowslot,
                       float* __restrict__ norms) {
  __shared__ float sx[256];
  const int i = blockIdx.x;
  const int d = threadIdx.x;  // 128 threads
  if (d == 0) {
    rowslot[i] = 0ull;
    if (i == 0) { norms[0] = 0.0f; norms[1] = 0.0f; }
  }
  sx[d] = x[i * 256 + d];
  sx[d + 128] = x[i * 256 + 128 + d];
  __syncthreads();
  double acc = 0.0;
  for (int k = 0; k < 256; ++k)
    acc = fma((double)sx[k], (double)W[k * 128 + d], acc);
  hraw[i * 128 + d] = (float)acc + b[d];
}

// ---------------- BN stats per column (f64) ----------------
__global__ void k_bnstats(const float* __restrict__ hraw,
                          float* __restrict__ meanv, float* __restrict__ rsv) {
  __shared__ double red[256];
  const int d = blockIdx.x;   // 128 blocks
  const int t = threadIdx.x;  // 256 threads
  double s = 0.0;
  for (int i = t; i < 2048; i += 256) s += (double)hraw[i * 128 + d];
  red[t] = s;
  __syncthreads();
  for (int off = 128; off > 0; off >>= 1) {
    if (t < off) red[t] += red[t + off];
    __syncthreads();
  }
  const float m = (float)(red[0] * (1.0 / 2048.0));
  __syncthreads();
  double v = 0.0;
  for (int i = t; i < 2048; i += 256) {
    float dd = __fsub_rn(hraw[i * 128 + d], m);
    v += (double)dd * (double)dd;
  }
  red[t] = v;
  __syncthreads();
  for (int off = 128; off > 0; off >>= 1) {
    if (t < off) red[t] += red[t + off];
    __syncthreads();
  }
  if (t == 0) {
    float var = (float)(red[0] * (1.0 / 2048.0));
    float vpe = __fadd_rn(var, 1e-5f);
    meanv[d] = m;
    rsv[d] = (float)(1.0 / sqrt((double)vpe));
  }
}

// ---------------- apply BN + leaky relu, emit bf16 copy + max row-norm ------
__global__ void k_apply(const float* __restrict__ hraw,
                        const float* __restrict__ meanv, const float* __restrict__ rsv,
                        const float* __restrict__ gamma, const float* __restrict__ beta,
                        float* __restrict__ hfin, unsigned short* __restrict__ hb,
                        float* __restrict__ norms) {
  __shared__ float red[256];
  const int t = threadIdx.x;
  const int idx = blockIdx.x * 256 + t;  // 2 rows per block
  const int d = idx & 127;
  float h = hraw[idx];
  float hn = __fadd_rn(__fmul_rn(__fmul_rn(__fsub_rn(h, meanv[d]), rsv[d]), gamma[d]), beta[d]);
  float o = (hn >= 0.0f) ? hn : __fmul_rn(0.01f, hn);
  hfin[idx] = o;
  hb[idx] = f2bf(o);
  red[t] = o * o;
  __syncthreads();
  for (int off = 64; off > 0; off >>= 1) {
    if ((t & 127) < off) red[t] += red[t + off];
    __syncthreads();
  }
  if ((t & 127) == 0) atomicMax((unsigned*)&norms[0], __float_as_uint(red[t]));
}

// ---------------- max item row-norm^2 ----------------
__global__ void k_anorm(const float* __restrict__ items, float* __restrict__ norms) {
  const int t = threadIdx.x;                 // 256
  const int row = blockIdx.x * 8 + (t >> 5); // 8 rows/block
  const int c = (t & 31) * 4;
  float4 v = *(const float4*)(items + (size_t)row * 128 + c);
  float ss = v.x * v.x + v.y * v.y + v.z * v.z + v.w * v.w;
  for (int m = 1; m <= 16; m <<= 1) ss += __shfl_xor(ss, m);
  if ((t & 31) == 0) atomicMax((unsigned*)&norms[1], __float_as_uint(ss));
}

// ---------------- V0 seed: per-row achieved max over j in [0,1024) ----------
__global__ __launch_bounds__(256, 4) void k_seed(const float* __restrict__ hfin,
                                                 const float* __restrict__ items,
                                                 float* __restrict__ V0) {
  __shared__ float red[4][256];
  const int t = threadIdx.x;
  const int rbase = blockIdx.x * 4;
  float best[4] = {-INFINITY, -INFINITY, -INFINITY, -INFINITY};
  for (int q = 0; q < 4; ++q) {
    const int j = t + 256 * q;
    float acc[4] = {0.0f, 0.0f, 0.0f, 0.0f};
    const float* ap = items + (size_t)j * 128;
    for (int km = 0; km < 8; ++km) {
#pragma unroll
      for (int e = 0; e < 4; ++e) {
        float4 a4 = *(const float4*)(ap + km * 16 + 4 * e);
#pragma unroll
        for (int p = 0; p < 4; ++p) {
          const float* hp = hfin + (rbase + p) * 128 + km * 16 + 4 * e;
          float4 h4 = *(const float4*)hp;  // uniform -> s_load
          acc[p] = fmaf(h4.x, a4.x, acc[p]);
          acc[p] = fmaf(h4.y, a4.y, acc[p]);
          acc[p] = fmaf(h4.z, a4.z, acc[p]);
          acc[p] = fmaf(h4.w, a4.w, acc[p]);
        }
      }
    }
#pragma unroll
    for (int p = 0; p < 4; ++p) {
      unsigned l = (unsigned)(rbase + p) * 50000u + (unsigned)j;
      float g = gumbel_from_bits(tf2x32_xor(0u, l));
      best[p] = fmaxf(best[p], acc[p] + g);
    }
  }
#pragma unroll
  for (int p = 0; p < 4; ++p) red[p][t] = best[p];
  __syncthreads();
  for (int off = 128; off > 0; off >>= 1) {
    if (t < off) {
#pragma unroll
      for (int p = 0; p < 4; ++p) red[p][t] = fmaxf(red[p][t], red[p][t + off]);
    }
    __syncthreads();
  }
  if (t < 4) V0[rbase + t] = red[t][0];
}

// ---------------- bf16 MFMA screen + exact fp32 rescore of survivors --------
// grid (8, 782): block = 256 rows x 64 j. 512 threads = 8 waves, each wave
// 32 rows x 64 j = 2 rowtiles x 4 jtiles of 16x16 MFMA output, K=128 via 4
// chained mfma_f32_16x16x32_bf16.
// Survivor criterion (never drops the true winner):
//   s_bf16 + ERRC + GMAX >= max(V0[r], best-so-far[r])
// ERRC >= |s_fp32 - s_bf16| via (2e+e^2)*||h||*||a|| + accum slack.
__global__ __launch_bounds__(512, 4) void k_screen(
    const unsigned short* __restrict__ hb, const float* __restrict__ hfin,
    const float* __restrict__ items, const float* __restrict__ V0,
    const float* __restrict__ norms, unsigned long long* __restrict__ rowslot) {
  __shared__ __align__(16) unsigned short Bs[64 * 128];  // 16KB swizzled bf16
  __shared__ unsigned qkey[QCAP2];                       // 16KB
  __shared__ float thrLds[256];
  __shared__ unsigned qcnt;

  const int t = threadIdx.x;
  const int r0 = blockIdx.x * 256;
  const int j0 = blockIdx.y * 64;
  const float ERRC = 0.004f * sqrtf(norms[0] * norms[1]) + 0.01f;

  if (t == 0) qcnt = 0;

  // ---- stage B tile: items fp32 -> bf16 LDS, XOR-swizzled ----
  {
    const int jl = t >> 3;            // 0..63
    const int c0 = (t & 7) * 16;      // float col base
    const int Jg = min(j0 + jl, 49999);
    const float4* src = (const float4*)(items + (size_t)Jg * 128 + c0);
    float4 f0 = src[0], f1 = src[1], f2 = src[2], f3 = src[3];
    uint4 A, Bv;
    A.x = pk2(f0.x, f0.y); A.y = pk2(f0.z, f0.w);
    A.z = pk2(f1.x, f1.y); A.w = pk2(f1.z, f1.w);
    Bv.x = pk2(f2.x, f2.y); Bv.y = pk2(f2.z, f2.w);
    Bv.z = pk2(f3.x, f3.y); Bv.w = pk2(f3.z, f3.w);
    const int byte0 = jl * 256 + c0 * 2;
    *(uint4*)((char*)Bs + bswz(byte0)) = A;
    *(uint4*)((char*)Bs + bswz(byte0 + 16)) = Bv;
  }
  // ---- per-row dynamic threshold (stale read is lower -> safe) ----
  if (t < 256) {
    const int R = r0 + t;
    unsigned long long pk = atomicMax(&rowslot[R], 0ull);  // atomic read
    float tv = V0[R];
    if (pk != 0ull) tv = fmaxf(tv, unordf((unsigned)(pk >> 32)));
    thrLds[t] = tv - GMAX - ERRC;
  }
  __syncthreads();

  const int w = t >> 6, l = t & 63;
  const int lg = l >> 4, lr = l & 15;

  f32x4 acc[2][4];
#pragma unroll
  for (int rt = 0; rt < 2; ++rt)
#pragma unroll
    for (int jt = 0; jt < 4; ++jt) acc[rt][jt] = (f32x4){0.f, 0.f, 0.f, 0.f};

  // A fragment: lane holds row (base + lr), 8 contiguous k at (kb*32 + lg*8)
  const unsigned short* aB0 = hb + (size_t)(r0 + w * 32 + lr) * 128 + lg * 8;
#pragma unroll
  for (int kb = 0; kb < 4; ++kb) {
    bf16x8 a0 = *(const bf16x8*)(aB0 + kb * 32);
    bf16x8 a1 = *(const bf16x8*)(aB0 + 16 * 128 + kb * 32);
#pragma unroll
    for (int jt = 0; jt < 4; ++jt) {
      const int byte = (jt * 16 + lr) * 256 + kb * 64 + lg * 16;
      bf16x8 bfrag = *(const bf16x8*)((char*)Bs + bswz(byte));
      acc[0][jt] = __builtin_amdgcn_mfma_f32_16x16x32_bf16(a0, bfrag, acc[0][jt], 0, 0, 0);
      acc[1][jt] = __builtin_amdgcn_mfma_f32_16x16x32_bf16(a1, bfrag, acc[1][jt], 0, 0, 0);
    }
  }

  // ---- push survivors (C/D: col = lane&15, row = (lane>>4)*4 + reg) ----
#pragma unroll
  for (int rt = 0; rt < 2; ++rt)
#pragma unroll
    for (int jt = 0; jt < 4; ++jt)
#pragma unroll
      for (int q = 0; q < 4; ++q) {
        const float s = acc[rt][jt][q];
        const int Rl = w * 32 + rt * 16 + lg * 4 + q;  // local row
        const int J = j0 + jt * 16 + lr;
        if (J < 50000 && s >= thrLds[Rl]) {
          const unsigned slot = atomicAdd(&qcnt, 1u);
          const unsigned key = ((unsigned)(r0 + Rl) << 16) | (unsigned)J;
          if (slot < QCAP2) {
            qkey[slot] = key;
          } else {  // overflow fallback: inline exact rescore (~never taken)
            const float* hp = hfin + (size_t)(r0 + Rl) * 128;
            const float* ap = items + (size_t)J * 128;
            float a = 0.0f;
            for (int k = 0; k < 32; ++k) {
              float4 h4 = *(const float4*)(hp + 4 * k);
              float4 a4 = *(const float4*)(ap + 4 * k);
              a = fmaf(h4.x, a4.x, a); a = fmaf(h4.y, a4.y, a);
              a = fmaf(h4.z, a4.z, a); a = fmaf(h4.w, a4.w, a);
            }
            const unsigned lc = (unsigned)(r0 + Rl) * 50000u + (unsigned)J;
            const float v = a + gumbel_from_bits(tf2x32_xor(0u, lc));
            const unsigned long long pkk =
                ((unsigned long long)ordf(v) << 32) | (0xFFFFFFFFu - (unsigned)J);
            atomicMax(&rowslot[r0 + Rl], pkk);
          }
        }
      }
  __syncthreads();

  // ---- exact fp32 rescore of queued survivors: 4 lanes per candidate ----
  const unsigned n = (qcnt < QCAP2) ? qcnt : QCAP2;
  const int gi = t >> 2, sub = t & 3;
  for (unsigned i = gi; i < n; i += 128) {
    const unsigned key = qkey[i];
    const int R = key >> 16;
    const int J = key & 0xFFFFu;
    const float* hp = hfin + (size_t)R * 128 + sub * 32;
    const float* ap = items + (size_t)J * 128 + sub * 32;
    float a = 0.0f;
#pragma unroll
    for (int k = 0; k < 8; ++k) {
      float4 h4 = *(const float4*)(hp + 4 * k);
      float4 a4 = *(const float4*)(ap + 4 * k);
      a = fmaf(h4.x, a4.x, a); a = fmaf(h4.y, a4.y, a);
      a = fmaf(h4.z, a4.z, a); a = fmaf(h4.w, a4.w, a);
    }
    a += __shfl_xor(a, 1);
    a += __shfl_xor(a, 2);
    if (sub == 0) {
      const unsigned lc = (unsigned)R * 50000u + (unsigned)J;
      const float v = a + gumbel_from_bits(tf2x32_xor(0u, lc));
      const unsigned long long pkk =
          ((unsigned long long)ordf(v) << 32) | (0xFFFFFFFFu - (unsigned)J);
      atomicMax(&rowslot[R], pkk);
    }
  }
}

// ---------------- final: read row winner + cosine sim (one wave/row) -------
__global__ void k_final(const unsigned long long* __restrict__ rowslot,
                        const int* __restrict__ uid, const float* __restrict__ items,
                        float* __restrict__ dout, float* __restrict__ simv) {
  const int r = blockIdx.x;
  const int lane = threadIdx.x;  // 64
  const unsigned long long pk = rowslot[r];  // nonzero: winner always pushed
  const int bi = (int)(0xFFFFFFFFu - (unsigned)pk);
  if (lane == 0) dout[r] = (float)bi;

  const int orig = uid[r * 2 + 1];
  float o1 = items[(size_t)orig * 128 + lane];
  float o2 = items[(size_t)orig * 128 + 64 + lane];
  float p1 = items[(size_t)bi * 128 + lane];
  float p2 = items[(size_t)bi * 128 + 64 + lane];
  float d = o1 * p1 + o2 * p2;
  float s1 = o1 * o1 + o2 * o2;
  float s2 = p1 * p1 + p2 * p2;
  for (int off = 32; off > 0; off >>= 1) {
    d += __shfl_down(d, off);
    s1 += __shfl_down(s1, off);
    s2 += __shfl_down(s2, off);
  }
  if (lane == 0) {
    float n1 = fmaxf(sqrtf(s1), 1e-6f);
    float n2 = fmaxf(sqrtf(s2), 1e-6f);
    float sim = d / (n1 * n2);
    simv[r] = (sim + 1.0f) * 0.5f;
  }
}

// ---------------- final scalar reductions ----------------
__global__ void k_reduce(const float* __restrict__ simv, float* __restrict__ dout) {
  __shared__ double rl[256];
  __shared__ double rs[256];
  const int t = threadIdx.x;
  double L = 0.0, S = 0.0;
  for (int i = t; i < 2048; i += 256) {
    double s = (double)simv[i];
    double dd = s - 0.5;
    L += dd * dd;
    S += s;
  }
  rl[t] = L; rs[t] = S;
  __syncthreads();
  for (int off = 128; off > 0; off >>= 1) {
    if (t < off) { rl[t] += rl[t + off]; rs[t] += rs[t + off]; }
    __syncthreads();
  }
  if (t == 0) {
    dout[2048] = (float)(rl[0] * (1.0 / 2048.0));
    dout[2049] = (float)(rs[0] * (1.0 / 2048.0));
  }
}

extern "C" void kernel_launch(void* const* d_in, const int* in_sizes, int n_in,
                              void* d_out, int out_size, void* d_ws, size_t ws_size,
                              hipStream_t stream) {
  const int* uid = (const int*)d_in[0];       // (2048,2) int32
  const float* xfeat = (const float*)d_in[1]; // (2048,256)
  const float* items = (const float*)d_in[2]; // (50000,128)
  const float* W = (const float*)d_in[3];     // (256,128)
  const float* bias = (const float*)d_in[4];  // (128,)
  const float* gamma = (const float*)d_in[5]; // (128,)
  const float* beta = (const float*)d_in[6];  // (128,)

  float* ws = (float*)d_ws;
  float* hraw = ws;                                   // 262144 f
  float* hfin = ws + 262144;                          // 262144 f
  float* meanv = ws + 524288;                         // 128 f
  float* rsv = ws + 524416;                           // 128 f
  float* V0 = ws + 524544;                            // 2048 f
  float* simv = ws + 526592;                          // 2048 f
  float* norms = ws + 528640;                         // 2 f (Hmax^2, Amax^2)
  unsigned long long* rowslot =
      (unsigned long long*)(ws + 528642);             // 2048 u64 (8B aligned)
  unsigned short* hb = (unsigned short*)(ws + 532740); // 262144 bf16 (16B aligned)
  float* dout = (float*)d_out;                        // 2050 floats

  hipLaunchKernelGGL(k_hraw, dim3(2048), dim3(128), 0, stream, xfeat, W, bias, hraw, rowslot, norms);
  hipLaunchKernelGGL(k_bnstats, dim3(128), dim3(256), 0, stream, hraw, meanv, rsv);
  hipLaunchKernelGGL(k_apply, dim3(1024), dim3(256), 0, stream, hraw, meanv, rsv, gamma, beta, hfin, hb, norms);
  hipLaunchKernelGGL(k_anorm, dim3(6250), dim3(256), 0, stream, items, norms);
  hipLaunchKernelGGL(k_seed, dim3(512), dim3(256), 0, stream, hfin, items, V0);
  hipLaunchKernelGGL(k_screen, dim3(8, 782), dim3(512), 0, stream, hb, hfin, items, V0, norms, rowslot);
  hipLaunchKernelGGL(k_final, dim3(2048), dim3(64), 0, stream, rowslot, uid, items, dout, simv);
  hipLaunchKernelGGL(k_reduce, dim3(1), dim3(256), 0, stream, simv, dout);
}

// Round 2
// 1035.501 us; speedup vs baseline: 1.2127x; 1.2127x over previous
//
#include <hip/hip_runtime.h>
#include <math.h>

#define TINYF 1.17549435e-38f
#define GMAX 16.0f   // hard upper bound on gumbel (15.9424) + slack
#define QCAP2 4096
#define JLOOP 8

typedef __attribute__((ext_vector_type(8))) short bf16x8;
typedef __attribute__((ext_vector_type(4))) float f32x4;

// ---------------- threefry2x32, key = (0, 42) ----------------
__device__ __forceinline__ unsigned rotl32(unsigned x, int r) {
  return (x << r) | (x >> (32 - r));
}

__device__ __forceinline__ unsigned tf2x32_xor(unsigned x0, unsigned x1) {
  const unsigned k0 = 0u, k1 = 42u, k2 = 0x1BD11BF0u;  // 0x1BD11BDA ^ 0 ^ 42
  x0 += k0; x1 += k1;
#define TFR(r) { x0 += x1; x1 = rotl32(x1, r); x1 ^= x0; }
  TFR(13) TFR(15) TFR(26) TFR(6)
  x0 += k1; x1 += k2 + 1u;
  TFR(17) TFR(29) TFR(16) TFR(24)
  x0 += k2; x1 += k0 + 2u;
  TFR(13) TFR(15) TFR(26) TFR(6)
  x0 += k0; x1 += k1 + 3u;
  TFR(17) TFR(29) TFR(16) TFR(24)
  x0 += k1; x1 += k2 + 4u;
  TFR(13) TFR(15) TFR(26) TFR(6)
  x0 += k2; x1 += k0 + 5u;
#undef TFR
  return x0 ^ x1;
}

__device__ __forceinline__ float gumbel_from_bits(unsigned bits) {
  float f = __uint_as_float((bits >> 9) | 0x3f800000u) - 1.0f;
  float u = fmaxf(f, TINYF);
  return -logf(-logf(u));
}

// order-preserving float->uint (monotone)
__device__ __forceinline__ unsigned ordf(float v) {
  unsigned b = __float_as_uint(v);
  return (b & 0x80000000u) ? ~b : (b | 0x80000000u);
}
__device__ __forceinline__ float unordf(unsigned u) {
  unsigned b = (u & 0x80000000u) ? (u & 0x7FFFFFFFu) : ~u;
  return __uint_as_float(b);
}

// fp32 -> bf16 RNE (bit trick)
__device__ __forceinline__ unsigned short f2bf(float f) {
  unsigned u = __float_as_uint(f);
  unsigned r = u + 0x7FFFu + ((u >> 16) & 1u);
  return (unsigned short)(r >> 16);
}
__device__ __forceinline__ unsigned pk2(float a, float b) {
  return (unsigned)f2bf(a) | ((unsigned)f2bf(b) << 16);
}
// LDS XOR swizzle for 256B-row tile (breaks 32-way ds_read_b128 conflict)
__device__ __forceinline__ int bswz(int b) { return b ^ (((b >> 8) & 7) << 4); }

// ---------------- h = x @ W + b (f64 accumulate) + workspace init ----------
__global__ void k_hraw(const float* __restrict__ x, const float* __restrict__ W,
                       const float* __restrict__ b, float* __restrict__ hraw,
                       unsigned long long* __restrict__ rowslot,
                       float* __restrict__ norms) {
  __shared__ float sx[256];
  const int i = blockIdx.x;
  const int d = threadIdx.x;  // 128 threads
  if (d == 0) {
    rowslot[i] = 0ull;
    if (i == 0) { norms[0] = 0.0f; norms[1] = 0.0f; }
  }
  sx[d] = x[i * 256 + d];
  sx[d + 128] = x[i * 256 + 128 + d];
  __syncthreads();
  double acc = 0.0;
  for (int k = 0; k < 256; ++k)
    acc = fma((double)sx[k], (double)W[k * 128 + d], acc);
  hraw[i * 128 + d] = (float)acc + b[d];
}

// ---------------- BN stats per column (f64) ----------------
__global__ void k_bnstats(const float* __restrict__ hraw,
                          float* __restrict__ meanv, float* __restrict__ rsv) {
  __shared__ double red[256];
  const int d = blockIdx.x;   // 128 blocks
  const int t = threadIdx.x;  // 256 threads
  double s = 0.0;
  for (int i = t; i < 2048; i += 256) s += (double)hraw[i * 128 + d];
  red[t] = s;
  __syncthreads();
  for (int off = 128; off > 0; off >>= 1) {
    if (t < off) red[t] += red[t + off];
    __syncthreads();
  }
  const float m = (float)(red[0] * (1.0 / 2048.0));
  __syncthreads();
  double v = 0.0;
  for (int i = t; i < 2048; i += 256) {
    float dd = __fsub_rn(hraw[i * 128 + d], m);
    v += (double)dd * (double)dd;
  }
  red[t] = v;
  __syncthreads();
  for (int off = 128; off > 0; off >>= 1) {
    if (t < off) red[t] += red[t + off];
    __syncthreads();
  }
  if (t == 0) {
    float var = (float)(red[0] * (1.0 / 2048.0));
    float vpe = __fadd_rn(var, 1e-5f);
    meanv[d] = m;
    rsv[d] = (float)(1.0 / sqrt((double)vpe));
  }
}

// ---------------- apply BN + leaky relu, emit bf16 copy + max row-norm ------
__global__ void k_apply(const float* __restrict__ hraw,
                        const float* __restrict__ meanv, const float* __restrict__ rsv,
                        const float* __restrict__ gamma, const float* __restrict__ beta,
                        float* __restrict__ hfin, unsigned short* __restrict__ hb,
                        float* __restrict__ norms) {
  __shared__ float red[256];
  const int t = threadIdx.x;
  const int idx = blockIdx.x * 256 + t;  // 2 rows per block
  const int d = idx & 127;
  float h = hraw[idx];
  float hn = __fadd_rn(__fmul_rn(__fmul_rn(__fsub_rn(h, meanv[d]), rsv[d]), gamma[d]), beta[d]);
  float o = (hn >= 0.0f) ? hn : __fmul_rn(0.01f, hn);
  hfin[idx] = o;
  hb[idx] = f2bf(o);
  red[t] = o * o;
  __syncthreads();
  for (int off = 64; off > 0; off >>= 1) {
    if ((t & 127) < off) red[t] += red[t + off];
    __syncthreads();
  }
  if ((t & 127) == 0) atomicMax((unsigned*)&norms[0], __float_as_uint(red[t]));
}

// ---------------- max item row-norm^2: one atomic per block ----------------
__global__ void k_anorm(const float* __restrict__ items, float* __restrict__ norms) {
  __shared__ float red[256];
  const int t = threadIdx.x;   // 256: 8 row-groups x 32 lanes
  const int r0 = blockIdx.x * 250;  // grid 200
  float mx = 0.0f;
  for (int rr = (t >> 5); rr < 250; rr += 8) {
    const float4 v = *(const float4*)(items + (size_t)(r0 + rr) * 128 + (t & 31) * 4);
    float ss = v.x * v.x + v.y * v.y + v.z * v.z + v.w * v.w;
    for (int m = 1; m <= 16; m <<= 1) ss += __shfl_xor(ss, m);
    mx = fmaxf(mx, ss);
  }
  red[t] = mx;
  __syncthreads();
  for (int off = 128; off > 0; off >>= 1) {
    if (t < off) red[t] = fmaxf(red[t], red[t + off]);
    __syncthreads();
  }
  if (t == 0) atomicMax((unsigned*)&norms[1], __float_as_uint(red[0]));
}

// ---------------- V0 seed: per-row achieved max over j in [0,1024) ----------
__global__ __launch_bounds__(256, 4) void k_seed(const float* __restrict__ hfin,
                                                 const float* __restrict__ items,
                                                 float* __restrict__ V0) {
  __shared__ float red[4][256];
  const int t = threadIdx.x;
  const int rbase = blockIdx.x * 4;
  float best[4] = {-INFINITY, -INFINITY, -INFINITY, -INFINITY};
  for (int q = 0; q < 4; ++q) {
    const int j = t + 256 * q;
    float acc[4] = {0.0f, 0.0f, 0.0f, 0.0f};
    const float* ap = items + (size_t)j * 128;
    for (int km = 0; km < 8; ++km) {
#pragma unroll
      for (int e = 0; e < 4; ++e) {
        float4 a4 = *(const float4*)(ap + km * 16 + 4 * e);
#pragma unroll
        for (int p = 0; p < 4; ++p) {
          const float* hp = hfin + (rbase + p) * 128 + km * 16 + 4 * e;
          float4 h4 = *(const float4*)hp;  // uniform -> s_load
          acc[p] = fmaf(h4.x, a4.x, acc[p]);
          acc[p] = fmaf(h4.y, a4.y, acc[p]);
          acc[p] = fmaf(h4.z, a4.z, acc[p]);
          acc[p] = fmaf(h4.w, a4.w, acc[p]);
        }
      }
    }
#pragma unroll
    for (int p = 0; p < 4; ++p) {
      unsigned l = (unsigned)(rbase + p) * 50000u + (unsigned)j;
      float g = gumbel_from_bits(tf2x32_xor(0u, l));
      best[p] = fmaxf(best[p], acc[p] + g);
    }
  }
#pragma unroll
  for (int p = 0; p < 4; ++p) red[p][t] = best[p];
  __syncthreads();
  for (int off = 128; off > 0; off >>= 1) {
    if (t < off) {
#pragma unroll
      for (int p = 0; p < 4; ++p) red[p][t] = fmaxf(red[p][t], red[p][t + off]);
    }
    __syncthreads();
  }
  if (t < 4) V0[rbase + t] = red[t][0];
}

// ---------------- bf16 MFMA screen + exact fp32 rescore of survivors --------
// grid (8, 98): block = 256 rows x (JLOOP x 64) j. 512 threads = 8 waves.
// A fragments stay resident in VGPRs across the j-loop.
// No atomic reads: per-row threshold comes from a PLAIN load of the hi word
// of rowslot[R] (monotone under atomicMax -> stale reads are lower -> safe;
// hi word alone is itself monotone, so no 64-bit tearing concern).
// Winner updates are guarded by the same plain hi-word read (skip only when
// strictly beaten; '>=' keeps the smaller-j tie-break path alive).
__global__ __launch_bounds__(512, 4) void k_screen(
    const unsigned short* __restrict__ hb, const float* __restrict__ hfin,
    const float* __restrict__ items, const float* __restrict__ V0,
    const float* __restrict__ norms, unsigned long long* __restrict__ rowslot) {
  __shared__ __align__(16) unsigned short Bs[64 * 128];  // 16KB swizzled bf16
  __shared__ unsigned qkey[QCAP2];                       // 16KB
  __shared__ float thrLds[256];
  __shared__ unsigned qcnt;

  const int t = threadIdx.x;
  const int r0 = blockIdx.x * 256;
  const float ERRC = 0.004f * sqrtf(norms[0] * norms[1]) + 0.01f;
  const volatile unsigned* hiw = (const volatile unsigned*)rowslot;  // hi at 2R+1

  const int w = t >> 6, l = t & 63;
  const int lg = l >> 4, lr = l & 15;

  // resident A fragments: lane holds row (r0 + w*32 [+16] + lr), 8 k each
  const unsigned short* aB0 = hb + (size_t)(r0 + w * 32 + lr) * 128 + lg * 8;
  bf16x8 Afrag[2][4];
#pragma unroll
  for (int kb = 0; kb < 4; ++kb) {
    Afrag[0][kb] = *(const bf16x8*)(aB0 + kb * 32);
    Afrag[1][kb] = *(const bf16x8*)(aB0 + 16 * 128 + kb * 32);
  }

  for (int it = 0; it < JLOOP; ++it) {
    const int j0 = (blockIdx.y * JLOOP + it) * 64;
    if (j0 >= 50000) break;

    __syncthreads();  // prev iter's Bs/qkey consumers done
    if (t == 0) qcnt = 0;

    // ---- stage B tile: items fp32 -> bf16 LDS, XOR-swizzled ----
    {
      const int jl = t >> 3;            // 0..63
      const int c0 = (t & 7) * 16;      // float col base
      const int Jg = min(j0 + jl, 49999);
      const float4* src = (const float4*)(items + (size_t)Jg * 128 + c0);
      float4 f0 = src[0], f1 = src[1], f2 = src[2], f3 = src[3];
      uint4 A, Bv;
      A.x = pk2(f0.x, f0.y); A.y = pk2(f0.z, f0.w);
      A.z = pk2(f1.x, f1.y); A.w = pk2(f1.z, f1.w);
      Bv.x = pk2(f2.x, f2.y); Bv.y = pk2(f2.z, f2.w);
      Bv.z = pk2(f3.x, f3.y); Bv.w = pk2(f3.z, f3.w);
      const int byte0 = jl * 256 + c0 * 2;
      *(uint4*)((char*)Bs + bswz(byte0)) = A;
      *(uint4*)((char*)Bs + bswz(byte0 + 16)) = Bv;
    }
    // ---- per-row dynamic threshold (plain load, stale-low is safe) ----
    if (t < 256) {
      const int R = r0 + t;
      const unsigned hi = hiw[2 * R + 1];
      float tv = V0[R];
      if (hi) tv = fmaxf(tv, unordf(hi));
      thrLds[t] = tv - GMAX - ERRC;
    }
    __syncthreads();

    f32x4 acc[2][4];
#pragma unroll
    for (int rt = 0; rt < 2; ++rt)
#pragma unroll
      for (int jt = 0; jt < 4; ++jt) acc[rt][jt] = (f32x4){0.f, 0.f, 0.f, 0.f};

#pragma unroll
    for (int kb = 0; kb < 4; ++kb) {
#pragma unroll
      for (int jt = 0; jt < 4; ++jt) {
        const int byte = (jt * 16 + lr) * 256 + kb * 64 + lg * 16;
        bf16x8 bfrag = *(const bf16x8*)((char*)Bs + bswz(byte));
        acc[0][jt] = __builtin_amdgcn_mfma_f32_16x16x32_bf16(Afrag[0][kb], bfrag, acc[0][jt], 0, 0, 0);
        acc[1][jt] = __builtin_amdgcn_mfma_f32_16x16x32_bf16(Afrag[1][kb], bfrag, acc[1][jt], 0, 0, 0);
      }
    }

    // ---- push survivors (C/D: col = lane&15, row = (lane>>4)*4 + reg) ----
#pragma unroll
    for (int rt = 0; rt < 2; ++rt)
#pragma unroll
      for (int jt = 0; jt < 4; ++jt)
#pragma unroll
        for (int q = 0; q < 4; ++q) {
          const float s = acc[rt][jt][q];
          const int Rl = w * 32 + rt * 16 + lg * 4 + q;  // local row
          const int J = j0 + jt * 16 + lr;
          if (J < 50000 && s >= thrLds[Rl]) {
            const unsigned slot = atomicAdd(&qcnt, 1u);
            const unsigned key = ((unsigned)(r0 + Rl) << 16) | (unsigned)J;
            if (slot < QCAP2) {
              qkey[slot] = key;
            } else {  // overflow fallback: inline exact rescore (~never taken)
              const float* hp = hfin + (size_t)(r0 + Rl) * 128;
              const float* ap = items + (size_t)J * 128;
              float a = 0.0f;
              for (int k = 0; k < 32; ++k) {
                float4 h4 = *(const float4*)(hp + 4 * k);
                float4 a4 = *(const float4*)(ap + 4 * k);
                a = fmaf(h4.x, a4.x, a); a = fmaf(h4.y, a4.y, a);
                a = fmaf(h4.z, a4.z, a); a = fmaf(h4.w, a4.w, a);
              }
              const unsigned lc = (unsigned)(r0 + Rl) * 50000u + (unsigned)J;
              const float v = a + gumbel_from_bits(tf2x32_xor(0u, lc));
              const unsigned ov = ordf(v);
              if (ov >= hiw[2 * (r0 + Rl) + 1]) {
                const unsigned long long pkk =
                    ((unsigned long long)ov << 32) | (0xFFFFFFFFu - (unsigned)J);
                atomicMax(&rowslot[r0 + Rl], pkk);
              }
            }
          }
        }
    __syncthreads();

    // ---- exact fp32 rescore of queued survivors: 4 lanes per candidate ----
    const unsigned n = (qcnt < QCAP2) ? qcnt : QCAP2;
    const int gi = t >> 2, sub = t & 3;
    for (unsigned i = gi; i < n; i += 128) {
      const unsigned key = qkey[i];
      const int R = key >> 16;
      const int J = key & 0xFFFFu;
      const float* hp = hfin + (size_t)R * 128 + sub * 32;
      const float* ap = items + (size_t)J * 128 + sub * 32;
      float a = 0.0f;
#pragma unroll
      for (int k = 0; k < 8; ++k) {
        float4 h4 = *(const float4*)(hp + 4 * k);
        float4 a4 = *(const float4*)(ap + 4 * k);
        a = fmaf(h4.x, a4.x, a); a = fmaf(h4.y, a4.y, a);
        a = fmaf(h4.z, a4.z, a); a = fmaf(h4.w, a4.w, a);
      }
      a += __shfl_xor(a, 1);
      a += __shfl_xor(a, 2);
      if (sub == 0) {
        const unsigned lc = (unsigned)R * 50000u + (unsigned)J;
        const float v = a + gumbel_from_bits(tf2x32_xor(0u, lc));
        const unsigned ov = ordf(v);
        if (ov >= hiw[2 * R + 1]) {  // guard: skip only when strictly beaten
          const unsigned long long pkk =
              ((unsigned long long)ov << 32) | (0xFFFFFFFFu - (unsigned)J);
          atomicMax(&rowslot[R], pkk);
        }
      }
    }
  }
}

// ---------------- final: read row winner + cosine sim (one wave/row) -------
__global__ void k_final(const unsigned long long* __restrict__ rowslot,
                        const int* __restrict__ uid, const float* __restrict__ items,
                        float* __restrict__ dout, float* __restrict__ simv) {
  const int r = blockIdx.x;
  const int lane = threadIdx.x;  // 64
  const unsigned long long pk = rowslot[r];  // nonzero: winner always pushed
  const int bi = (int)(0xFFFFFFFFu - (unsigned)pk);
  if (lane == 0) dout[r] = (float)bi;

  const int orig = uid[r * 2 + 1];
  float o1 = items[(size_t)orig * 128 + lane];
  float o2 = items[(size_t)orig * 128 + 64 + lane];
  float p1 = items[(size_t)bi * 128 + lane];
  float p2 = items[(size_t)bi * 128 + 64 + lane];
  float d = o1 * p1 + o2 * p2;
  float s1 = o1 * o1 + o2 * o2;
  float s2 = p1 * p1 + p2 * p2;
  for (int off = 32; off > 0; off >>= 1) {
    d += __shfl_down(d, off);
    s1 += __shfl_down(s1, off);
    s2 += __shfl_down(s2, off);
  }
  if (lane == 0) {
    float n1 = fmaxf(sqrtf(s1), 1e-6f);
    float n2 = fmaxf(sqrtf(s2), 1e-6f);
    float sim = d / (n1 * n2);
    simv[r] = (sim + 1.0f) * 0.5f;
  }
}

// ---------------- final scalar reductions ----------------
__global__ void k_reduce(const float* __restrict__ simv, float* __restrict__ dout) {
  __shared__ double rl[256];
  __shared__ double rs[256];
  const int t = threadIdx.x;
  double L = 0.0, S = 0.0;
  for (int i = t; i < 2048; i += 256) {
    double s = (double)simv[i];
    double dd = s - 0.5;
    L += dd * dd;
    S += s;
  }
  rl[t] = L; rs[t] = S;
  __syncthreads();
  for (int off = 128; off > 0; off >>= 1) {
    if (t < off) { rl[t] += rl[t + off]; rs[t] += rs[t + off]; }
    __syncthreads();
  }
  if (t == 0) {
    dout[2048] = (float)(rl[0] * (1.0 / 2048.0));
    dout[2049] = (float)(rs[0] * (1.0 / 2048.0));
  }
}

extern "C" void kernel_launch(void* const* d_in, const int* in_sizes, int n_in,
                              void* d_out, int out_size, void* d_ws, size_t ws_size,
                              hipStream_t stream) {
  const int* uid = (const int*)d_in[0];       // (2048,2) int32
  const float* xfeat = (const float*)d_in[1]; // (2048,256)
  const float* items = (const float*)d_in[2]; // (50000,128)
  const float* W = (const float*)d_in[3];     // (256,128)
  const float* bias = (const float*)d_in[4];  // (128,)
  const float* gamma = (const float*)d_in[5]; // (128,)
  const float* beta = (const float*)d_in[6];  // (128,)

  float* ws = (float*)d_ws;
  float* hraw = ws;                                   // 262144 f
  float* hfin = ws + 262144;                          // 262144 f
  float* meanv = ws + 524288;                         // 128 f
  float* rsv = ws + 524416;                           // 128 f
  float* V0 = ws + 524544;                            // 2048 f
  float* simv = ws + 526592;                          // 2048 f
  float* norms = ws + 528640;                         // 2 f (Hmax^2, Amax^2)
  unsigned long long* rowslot =
      (unsigned long long*)(ws + 528642);             // 2048 u64 (8B aligned)
  unsigned short* hb = (unsigned short*)(ws + 532740); // 262144 bf16 (16B aligned)
  float* dout = (float*)d_out;                        // 2050 floats

  hipLaunchKernelGGL(k_hraw, dim3(2048), dim3(128), 0, stream, xfeat, W, bias, hraw, rowslot, norms);
  hipLaunchKernelGGL(k_bnstats, dim3(128), dim3(256), 0, stream, hraw, meanv, rsv);
  hipLaunchKernelGGL(k_apply, dim3(1024), dim3(256), 0, stream, hraw, meanv, rsv, gamma, beta, hfin, hb, norms);
  hipLaunchKernelGGL(k_anorm, dim3(200), dim3(256), 0, stream, items, norms);
  hipLaunchKernelGGL(k_seed, dim3(512), dim3(256), 0, stream, hfin, items, V0);
  hipLaunchKernelGGL(k_screen, dim3(8, 98), dim3(512), 0, stream, hb, hfin, items, V0, norms, rowslot);
  hipLaunchKernelGGL(k_final, dim3(2048), dim3(64), 0, stream, rowslot, uid, items, dout, simv);
  hipLaunchKernelGGL(k_reduce, dim3(1), dim3(256), 0, stream, simv, dout);
}

// Round 3
// 1024.507 us; speedup vs baseline: 1.2257x; 1.0107x over previous
//
#include <hip/hip_runtime.h>
#include <math.h>

#define TINYF 1.17549435e-38f
#define GMAX 16.0f   // hard upper bound on gumbel (15.9424) + slack
#define QCAP2 4096
#define JLOOP 8

typedef __attribute__((ext_vector_type(8))) short bf16x8;
typedef __attribute__((ext_vector_type(4))) float f32x4;

// ---------------- threefry2x32, key = (0, 42) ----------------
__device__ __forceinline__ unsigned rotl32(unsigned x, int r) {
  return (x << r) | (x >> (32 - r));
}

__device__ __forceinline__ unsigned tf2x32_xor(unsigned x0, unsigned x1) {
  const unsigned k0 = 0u, k1 = 42u, k2 = 0x1BD11BF0u;  // 0x1BD11BDA ^ 0 ^ 42
  x0 += k0; x1 += k1;
#define TFR(r) { x0 += x1; x1 = rotl32(x1, r); x1 ^= x0; }
  TFR(13) TFR(15) TFR(26) TFR(6)
  x0 += k1; x1 += k2 + 1u;
  TFR(17) TFR(29) TFR(16) TFR(24)
  x0 += k2; x1 += k0 + 2u;
  TFR(13) TFR(15) TFR(26) TFR(6)
  x0 += k0; x1 += k1 + 3u;
  TFR(17) TFR(29) TFR(16) TFR(24)
  x0 += k1; x1 += k2 + 4u;
  TFR(13) TFR(15) TFR(26) TFR(6)
  x0 += k2; x1 += k0 + 5u;
#undef TFR
  return x0 ^ x1;
}

__device__ __forceinline__ float gumbel_from_bits(unsigned bits) {
  float f = __uint_as_float((bits >> 9) | 0x3f800000u) - 1.0f;
  float u = fmaxf(f, TINYF);
  return -logf(-logf(u));
}

// order-preserving float->uint (monotone)
__device__ __forceinline__ unsigned ordf(float v) {
  unsigned b = __float_as_uint(v);
  return (b & 0x80000000u) ? ~b : (b | 0x80000000u);
}
__device__ __forceinline__ float unordf(unsigned u) {
  unsigned b = (u & 0x80000000u) ? (u & 0x7FFFFFFFu) : ~u;
  return __uint_as_float(b);
}

// fp32 -> bf16 RNE (bit trick)
__device__ __forceinline__ unsigned short f2bf(float f) {
  unsigned u = __float_as_uint(f);
  unsigned r = u + 0x7FFFu + ((u >> 16) & 1u);
  return (unsigned short)(r >> 16);
}
__device__ __forceinline__ unsigned pk2(float a, float b) {
  return (unsigned)f2bf(a) | ((unsigned)f2bf(b) << 16);
}
// LDS XOR swizzle for 256B-row tile (breaks 32-way ds_read_b128 conflict)
__device__ __forceinline__ int bswz(int b) { return b ^ (((b >> 8) & 7) << 4); }

// ---------------- h = x @ W + b (f64 accumulate) + workspace init ----------
__global__ void k_hraw(const float* __restrict__ x, const float* __restrict__ W,
                       const float* __restrict__ b, float* __restrict__ hraw,
                       unsigned long long* __restrict__ rowslot,
                       float* __restrict__ norms) {
  __shared__ float sx[256];
  const int i = blockIdx.x;
  const int d = threadIdx.x;  // 128 threads
  if (d == 0) {
    rowslot[i] = 0ull;
    if (i == 0) { norms[0] = 0.0f; norms[1] = 0.0f; }
  }
  sx[d] = x[i * 256 + d];
  sx[d + 128] = x[i * 256 + 128 + d];
  __syncthreads();
  double acc = 0.0;
  for (int k = 0; k < 256; ++k)
    acc = fma((double)sx[k], (double)W[k * 128 + d], acc);
  hraw[i * 128 + d] = (float)acc + b[d];
}

// ---------------- BN stats per column (f64) ----------------
__global__ void k_bnstats(const float* __restrict__ hraw,
                          float* __restrict__ meanv, float* __restrict__ rsv) {
  __shared__ double red[256];
  const int d = blockIdx.x;   // 128 blocks
  const int t = threadIdx.x;  // 256 threads
  double s = 0.0;
  for (int i = t; i < 2048; i += 256) s += (double)hraw[i * 128 + d];
  red[t] = s;
  __syncthreads();
  for (int off = 128; off > 0; off >>= 1) {
    if (t < off) red[t] += red[t + off];
    __syncthreads();
  }
  const float m = (float)(red[0] * (1.0 / 2048.0));
  __syncthreads();
  double v = 0.0;
  for (int i = t; i < 2048; i += 256) {
    float dd = __fsub_rn(hraw[i * 128 + d], m);
    v += (double)dd * (double)dd;
  }
  red[t] = v;
  __syncthreads();
  for (int off = 128; off > 0; off >>= 1) {
    if (t < off) red[t] += red[t + off];
    __syncthreads();
  }
  if (t == 0) {
    float var = (float)(red[0] * (1.0 / 2048.0));
    float vpe = __fadd_rn(var, 1e-5f);
    meanv[d] = m;
    rsv[d] = (float)(1.0 / sqrt((double)vpe));
  }
}

// ---------------- apply BN + leaky relu, emit bf16 copy + max row-norm ------
__global__ void k_apply(const float* __restrict__ hraw,
                        const float* __restrict__ meanv, const float* __restrict__ rsv,
                        const float* __restrict__ gamma, const float* __restrict__ beta,
                        float* __restrict__ hfin, unsigned short* __restrict__ hb,
                        float* __restrict__ norms) {
  __shared__ float red[256];
  const int t = threadIdx.x;
  const int idx = blockIdx.x * 256 + t;  // 2 rows per block
  const int d = idx & 127;
  float h = hraw[idx];
  float hn = __fadd_rn(__fmul_rn(__fmul_rn(__fsub_rn(h, meanv[d]), rsv[d]), gamma[d]), beta[d]);
  float o = (hn >= 0.0f) ? hn : __fmul_rn(0.01f, hn);
  hfin[idx] = o;
  hb[idx] = f2bf(o);
  red[t] = o * o;
  __syncthreads();
  for (int off = 64; off > 0; off >>= 1) {
    if ((t & 127) < off) red[t] += red[t + off];
    __syncthreads();
  }
  if ((t & 127) == 0) atomicMax((unsigned*)&norms[0], __float_as_uint(red[t]));
}

// ---------------- max item row-norm^2: one atomic per block ----------------
__global__ void k_anorm(const float* __restrict__ items, float* __restrict__ norms) {
  __shared__ float red[256];
  const int t = threadIdx.x;   // 256: 8 row-groups x 32 lanes
  const int r0 = blockIdx.x * 250;  // grid 200
  float mx = 0.0f;
  for (int rr = (t >> 5); rr < 250; rr += 8) {
    const float4 v = *(const float4*)(items + (size_t)(r0 + rr) * 128 + (t & 31) * 4);
    float ss = v.x * v.x + v.y * v.y + v.z * v.z + v.w * v.w;
    for (int m = 1; m <= 16; m <<= 1) ss += __shfl_xor(ss, m);
    mx = fmaxf(mx, ss);
  }
  red[t] = mx;
  __syncthreads();
  for (int off = 128; off > 0; off >>= 1) {
    if (t < off) red[t] = fmaxf(red[t], red[t + off]);
    __syncthreads();
  }
  if (t == 0) atomicMax((unsigned*)&norms[1], __float_as_uint(red[0]));
}

// ---------------- V0 seed: per-row achieved max over j in [0,1024) ----------
__global__ __launch_bounds__(256, 4) void k_seed(const float* __restrict__ hfin,
                                                 const float* __restrict__ items,
                                                 float* __restrict__ V0) {
  __shared__ float red[4][256];
  const int t = threadIdx.x;
  const int rbase = blockIdx.x * 4;
  float best[4] = {-INFINITY, -INFINITY, -INFINITY, -INFINITY};
  for (int q = 0; q < 4; ++q) {
    const int j = t + 256 * q;
    float acc[4] = {0.0f, 0.0f, 0.0f, 0.0f};
    const float* ap = items + (size_t)j * 128;
    for (int km = 0; km < 8; ++km) {
#pragma unroll
      for (int e = 0; e < 4; ++e) {
        float4 a4 = *(const float4*)(ap + km * 16 + 4 * e);
#pragma unroll
        for (int p = 0; p < 4; ++p) {
          const float* hp = hfin + (rbase + p) * 128 + km * 16 + 4 * e;
          float4 h4 = *(const float4*)hp;  // uniform -> s_load
          acc[p] = fmaf(h4.x, a4.x, acc[p]);
          acc[p] = fmaf(h4.y, a4.y, acc[p]);
          acc[p] = fmaf(h4.z, a4.z, acc[p]);
          acc[p] = fmaf(h4.w, a4.w, acc[p]);
        }
      }
    }
#pragma unroll
    for (int p = 0; p < 4; ++p) {
      unsigned l = (unsigned)(rbase + p) * 50000u + (unsigned)j;
      float g = gumbel_from_bits(tf2x32_xor(0u, l));
      best[p] = fmaxf(best[p], acc[p] + g);
    }
  }
#pragma unroll
  for (int p = 0; p < 4; ++p) red[p][t] = best[p];
  __syncthreads();
  for (int off = 128; off > 0; off >>= 1) {
    if (t < off) {
#pragma unroll
      for (int p = 0; p < 4; ++p) red[p][t] = fmaxf(red[p][t], red[p][t + off]);
    }
    __syncthreads();
  }
  if (t < 4) V0[rbase + t] = red[t][0];
}

// ---------------- bf16 MFMA screen + exact fp32 rescore of survivors --------
// grid (8, 98): block = 256 rows x (JLOOP x 64) j. 512 threads = 8 waves.
// A fragments stay resident in VGPRs across the j-loop.
// __launch_bounds__(512, 2): 2 blocks/CU = 16 waves/CU -> 128-VGPR budget.
// (At (512,4) the compiler capped at 64 VGPRs and spilled acc+Afrag to
// scratch every iteration -> 411 MB WRITE_SIZE, 869us. Live set ~100 VGPRs.)
__global__ __launch_bounds__(512, 2) void k_screen(
    const unsigned short* __restrict__ hb, const float* __restrict__ hfin,
    const float* __restrict__ items, const float* __restrict__ V0,
    const float* __restrict__ norms, unsigned long long* __restrict__ rowslot) {
  __shared__ __align__(16) unsigned short Bs[64 * 128];  // 16KB swizzled bf16
  __shared__ unsigned qkey[QCAP2];                       // 16KB
  __shared__ float thrLds[256];
  __shared__ unsigned qcnt;

  const int t = threadIdx.x;
  const int r0 = blockIdx.x * 256;
  const float ERRC = 0.004f * sqrtf(norms[0] * norms[1]) + 0.01f;
  const volatile unsigned* hiw = (const volatile unsigned*)rowslot;  // hi at 2R+1

  const int w = t >> 6, l = t & 63;
  const int lg = l >> 4, lr = l & 15;

  // resident A fragments: lane holds row (r0 + w*32 [+16] + lr), 8 k each
  const unsigned short* aB0 = hb + (size_t)(r0 + w * 32 + lr) * 128 + lg * 8;
  bf16x8 Afrag[2][4];
#pragma unroll
  for (int kb = 0; kb < 4; ++kb) {
    Afrag[0][kb] = *(const bf16x8*)(aB0 + kb * 32);
    Afrag[1][kb] = *(const bf16x8*)(aB0 + 16 * 128 + kb * 32);
  }

  for (int it = 0; it < JLOOP; ++it) {
    const int j0 = (blockIdx.y * JLOOP + it) * 64;
    if (j0 >= 50000) break;

    __syncthreads();  // prev iter's Bs/qkey consumers done
    if (t == 0) qcnt = 0;

    // ---- stage B tile: items fp32 -> bf16 LDS, XOR-swizzled ----
    {
      const int jl = t >> 3;            // 0..63
      const int c0 = (t & 7) * 16;      // float col base
      const int Jg = min(j0 + jl, 49999);
      const float4* src = (const float4*)(items + (size_t)Jg * 128 + c0);
      float4 f0 = src[0], f1 = src[1], f2 = src[2], f3 = src[3];
      uint4 A, Bv;
      A.x = pk2(f0.x, f0.y); A.y = pk2(f0.z, f0.w);
      A.z = pk2(f1.x, f1.y); A.w = pk2(f1.z, f1.w);
      Bv.x = pk2(f2.x, f2.y); Bv.y = pk2(f2.z, f2.w);
      Bv.z = pk2(f3.x, f3.y); Bv.w = pk2(f3.z, f3.w);
      const int byte0 = jl * 256 + c0 * 2;
      *(uint4*)((char*)Bs + bswz(byte0)) = A;
      *(uint4*)((char*)Bs + bswz(byte0 + 16)) = Bv;
    }
    // ---- per-row dynamic threshold (plain load, stale-low is safe) ----
    if (t < 256) {
      const int R = r0 + t;
      const unsigned hi = hiw[2 * R + 1];
      float tv = V0[R];
      if (hi) tv = fmaxf(tv, unordf(hi));
      thrLds[t] = tv - GMAX - ERRC;
    }
    __syncthreads();

    f32x4 acc[2][4];
#pragma unroll
    for (int rt = 0; rt < 2; ++rt)
#pragma unroll
      for (int jt = 0; jt < 4; ++jt) acc[rt][jt] = (f32x4){0.f, 0.f, 0.f, 0.f};

#pragma unroll
    for (int kb = 0; kb < 4; ++kb) {
#pragma unroll
      for (int jt = 0; jt < 4; ++jt) {
        const int byte = (jt * 16 + lr) * 256 + kb * 64 + lg * 16;
        bf16x8 bfrag = *(const bf16x8*)((char*)Bs + bswz(byte));
        acc[0][jt] = __builtin_amdgcn_mfma_f32_16x16x32_bf16(Afrag[0][kb], bfrag, acc[0][jt], 0, 0, 0);
        acc[1][jt] = __builtin_amdgcn_mfma_f32_16x16x32_bf16(Afrag[1][kb], bfrag, acc[1][jt], 0, 0, 0);
      }
    }

    // ---- push survivors (C/D: col = lane&15, row = (lane>>4)*4 + reg) ----
#pragma unroll
    for (int rt = 0; rt < 2; ++rt)
#pragma unroll
      for (int jt = 0; jt < 4; ++jt)
#pragma unroll
        for (int q = 0; q < 4; ++q) {
          const float s = acc[rt][jt][q];
          const int Rl = w * 32 + rt * 16 + lg * 4 + q;  // local row
          const int J = j0 + jt * 16 + lr;
          if (J < 50000 && s >= thrLds[Rl]) {
            const unsigned slot = atomicAdd(&qcnt, 1u);
            const unsigned key = ((unsigned)(r0 + Rl) << 16) | (unsigned)J;
            if (slot < QCAP2) {
              qkey[slot] = key;
            } else {  // overflow fallback: inline exact rescore (~never taken)
              const float* hp = hfin + (size_t)(r0 + Rl) * 128;
              const float* ap = items + (size_t)J * 128;
              float a = 0.0f;
              for (int k = 0; k < 32; ++k) {
                float4 h4 = *(const float4*)(hp + 4 * k);
                float4 a4 = *(const float4*)(ap + 4 * k);
                a = fmaf(h4.x, a4.x, a); a = fmaf(h4.y, a4.y, a);
                a = fmaf(h4.z, a4.z, a); a = fmaf(h4.w, a4.w, a);
              }
              const unsigned lc = (unsigned)(r0 + Rl) * 50000u + (unsigned)J;
              const float v = a + gumbel_from_bits(tf2x32_xor(0u, lc));
              const unsigned ov = ordf(v);
              if (ov >= hiw[2 * (r0 + Rl) + 1]) {
                const unsigned long long pkk =
                    ((unsigned long long)ov << 32) | (0xFFFFFFFFu - (unsigned)J);
                atomicMax(&rowslot[r0 + Rl], pkk);
              }
            }
          }
        }
    __syncthreads();

    // ---- exact fp32 rescore of queued survivors: 4 lanes per candidate ----
    const unsigned n = (qcnt < QCAP2) ? qcnt : QCAP2;
    const int gi = t >> 2, sub = t & 3;
    for (unsigned i = gi; i < n; i += 128) {
      const unsigned key = qkey[i];
      const int R = key >> 16;
      const int J = key & 0xFFFFu;
      const float* hp = hfin + (size_t)R * 128 + sub * 32;
      const float* ap = items + (size_t)J * 128 + sub * 32;
      float a = 0.0f;
#pragma unroll
      for (int k = 0; k < 8; ++k) {
        float4 h4 = *(const float4*)(hp + 4 * k);
        float4 a4 = *(const float4*)(ap + 4 * k);
        a = fmaf(h4.x, a4.x, a); a = fmaf(h4.y, a4.y, a);
        a = fmaf(h4.z, a4.z, a); a = fmaf(h4.w, a4.w, a);
      }
      a += __shfl_xor(a, 1);
      a += __shfl_xor(a, 2);
      if (sub == 0) {
        const unsigned lc = (unsigned)R * 50000u + (unsigned)J;
        const float v = a + gumbel_from_bits(tf2x32_xor(0u, lc));
        const unsigned ov = ordf(v);
        if (ov >= hiw[2 * R + 1]) {  // guard: skip only when strictly beaten
          const unsigned long long pkk =
              ((unsigned long long)ov << 32) | (0xFFFFFFFFu - (unsigned)J);
          atomicMax(&rowslot[R], pkk);
        }
      }
    }
  }
}

// ---------------- final: read row winner + cosine sim (one wave/row) -------
__global__ void k_final(const unsigned long long* __restrict__ rowslot,
                        const int* __restrict__ uid, const float* __restrict__ items,
                        float* __restrict__ dout, float* __restrict__ simv) {
  const int r = blockIdx.x;
  const int lane = threadIdx.x;  // 64
  const unsigned long long pk = rowslot[r];  // nonzero: winner always pushed
  const int bi = (int)(0xFFFFFFFFu - (unsigned)pk);
  if (lane == 0) dout[r] = (float)bi;

  const int orig = uid[r * 2 + 1];
  float o1 = items[(size_t)orig * 128 + lane];
  float o2 = items[(size_t)orig * 128 + 64 + lane];
  float p1 = items[(size_t)bi * 128 + lane];
  float p2 = items[(size_t)bi * 128 + 64 + lane];
  float d = o1 * p1 + o2 * p2;
  float s1 = o1 * o1 + o2 * o2;
  float s2 = p1 * p1 + p2 * p2;
  for (int off = 32; off > 0; off >>= 1) {
    d += __shfl_down(d, off);
    s1 += __shfl_down(s1, off);
    s2 += __shfl_down(s2, off);
  }
  if (lane == 0) {
    float n1 = fmaxf(sqrtf(s1), 1e-6f);
    float n2 = fmaxf(sqrtf(s2), 1e-6f);
    float sim = d / (n1 * n2);
    simv[r] = (sim + 1.0f) * 0.5f;
  }
}

// ---------------- final scalar reductions ----------------
__global__ void k_reduce(const float* __restrict__ simv, float* __restrict__ dout) {
  __shared__ double rl[256];
  __shared__ double rs[256];
  const int t = threadIdx.x;
  double L = 0.0, S = 0.0;
  for (int i = t; i < 2048; i += 256) {
    double s = (double)simv[i];
    double dd = s - 0.5;
    L += dd * dd;
    S += s;
  }
  rl[t] = L; rs[t] = S;
  __syncthreads();
  for (int off = 128; off > 0; off >>= 1) {
    if (t < off) { rl[t] += rl[t + off]; rs[t] += rs[t + off]; }
    __syncthreads();
  }
  if (t == 0) {
    dout[2048] = (float)(rl[0] * (1.0 / 2048.0));
    dout[2049] = (float)(rs[0] * (1.0 / 2048.0));
  }
}

extern "C" void kernel_launch(void* const* d_in, const int* in_sizes, int n_in,
                              void* d_out, int out_size, void* d_ws, size_t ws_size,
                              hipStream_t stream) {
  const int* uid = (const int*)d_in[0];       // (2048,2) int32
  const float* xfeat = (const float*)d_in[1]; // (2048,256)
  const float* items = (const float*)d_in[2]; // (50000,128)
  const float* W = (const float*)d_in[3];     // (256,128)
  const float* bias = (const float*)d_in[4];  // (128,)
  const float* gamma = (const float*)d_in[5]; // (128,)
  const float* beta = (const float*)d_in[6];  // (128,)

  float* ws = (float*)d_ws;
  float* hraw = ws;                                   // 262144 f
  float* hfin = ws + 262144;                          // 262144 f
  float* meanv = ws + 524288;                         // 128 f
  float* rsv = ws + 524416;                           // 128 f
  float* V0 = ws + 524544;                            // 2048 f
  float* simv = ws + 526592;                          // 2048 f
  float* norms = ws + 528640;                         // 2 f (Hmax^2, Amax^2)
  unsigned long long* rowslot =
      (unsigned long long*)(ws + 528642);             // 2048 u64 (8B aligned)
  unsigned short* hb = (unsigned short*)(ws + 532740); // 262144 bf16 (16B aligned)
  float* dout = (float*)d_out;                        // 2050 floats

  hipLaunchKernelGGL(k_hraw, dim3(2048), dim3(128), 0, stream, xfeat, W, bias, hraw, rowslot, norms);
  hipLaunchKernelGGL(k_bnstats, dim3(128), dim3(256), 0, stream, hraw, meanv, rsv);
  hipLaunchKernelGGL(k_apply, dim3(1024), dim3(256), 0, stream, hraw, meanv, rsv, gamma, beta, hfin, hb, norms);
  hipLaunchKernelGGL(k_anorm, dim3(200), dim3(256), 0, stream, items, norms);
  hipLaunchKernelGGL(k_seed, dim3(512), dim3(256), 0, stream, hfin, items, V0);
  hipLaunchKernelGGL(k_screen, dim3(8, 98), dim3(512), 0, stream, hb, hfin, items, V0, norms, rowslot);
  hipLaunchKernelGGL(k_final, dim3(2048), dim3(64), 0, stream, rowslot, uid, items, dout, simv);
  hipLaunchKernelGGL(k_reduce, dim3(1), dim3(256), 0, stream, simv, dout);
}

// Round 5
// 465.525 us; speedup vs baseline: 2.6975x; 2.2008x over previous
//
#include <hip/hip_runtime.h>
#include <math.h>

#define TINYF 1.17549435e-38f
#define GMAX 16.0f   // hard upper bound on gumbel (15.9424) + slack
#define QCAP 4096
#define JLOOP 16     // 16 x 32-j inner tiles per block -> 512 j per block

typedef __attribute__((ext_vector_type(8))) short bf16x8;
typedef __attribute__((ext_vector_type(4))) float f32x4;

// ---------------- threefry2x32, key = (0, 42) ----------------
__device__ __forceinline__ unsigned rotl32(unsigned x, int r) {
  return (x << r) | (x >> (32 - r));
}

__device__ __forceinline__ unsigned tf2x32_xor(unsigned x0, unsigned x1) {
  const unsigned k0 = 0u, k1 = 42u, k2 = 0x1BD11BF0u;  // 0x1BD11BDA ^ 0 ^ 42
  x0 += k0; x1 += k1;
#define TFR(r) { x0 += x1; x1 = rotl32(x1, r); x1 ^= x0; }
  TFR(13) TFR(15) TFR(26) TFR(6)
  x0 += k1; x1 += k2 + 1u;
  TFR(17) TFR(29) TFR(16) TFR(24)
  x0 += k2; x1 += k0 + 2u;
  TFR(13) TFR(15) TFR(26) TFR(6)
  x0 += k0; x1 += k1 + 3u;
  TFR(17) TFR(29) TFR(16) TFR(24)
  x0 += k1; x1 += k2 + 4u;
  TFR(13) TFR(15) TFR(26) TFR(6)
  x0 += k2; x1 += k0 + 5u;
#undef TFR
  return x0 ^ x1;
}

__device__ __forceinline__ float gumbel_from_bits(unsigned bits) {
  float f = __uint_as_float((bits >> 9) | 0x3f800000u) - 1.0f;
  float u = fmaxf(f, TINYF);
  return -logf(-logf(u));
}

// order-preserving float->uint (monotone)
__device__ __forceinline__ unsigned ordf(float v) {
  unsigned b = __float_as_uint(v);
  return (b & 0x80000000u) ? ~b : (b | 0x80000000u);
}
__device__ __forceinline__ float unordf(unsigned u) {
  unsigned b = (u & 0x80000000u) ? (u & 0x7FFFFFFFu) : ~u;
  return __uint_as_float(b);
}

// fp32 -> bf16 RNE (bit trick)
__device__ __forceinline__ unsigned short f2bf(float f) {
  unsigned u = __float_as_uint(f);
  unsigned r = u + 0x7FFFu + ((u >> 16) & 1u);
  return (unsigned short)(r >> 16);
}
__device__ __forceinline__ unsigned pk2(float a, float b) {
  return (unsigned)f2bf(a) | ((unsigned)f2bf(b) << 16);
}
// LDS XOR swizzle for 256B-row tile (breaks 32-way ds_read_b128 conflict)
__device__ __forceinline__ int bswz(int b) { return b ^ (((b >> 8) & 7) << 4); }

// ---- candidate resolution: gumbel, tier-2 test, exact fp32 dot, atomicMax.
// ONE copy (noinline) -- shared by queue flush and overflow path. The 32x
// inlined version of this was the round-1..3 killer (code bloat -> spill).
__device__ __attribute__((noinline)) void resolve_cand(
    int R, int J, float s, float thr2,
    const float* __restrict__ hfin, const float* __restrict__ items,
    unsigned long long* __restrict__ rowslot, const volatile unsigned* hiw) {
  const unsigned lc = (unsigned)R * 50000u + (unsigned)J;
  const float g = gumbel_from_bits(tf2x32_xor(0u, lc));
  if (s + g < thr2) return;  // sound: s_fp32 + g <= s_bf16 + ERRC + g
  const float4* hp = (const float4*)(hfin + (size_t)R * 128);
  const float4* ap = (const float4*)(items + (size_t)J * 128);
  float4 a4 = {0.f, 0.f, 0.f, 0.f};
#pragma unroll
  for (int k = 0; k < 32; ++k) {
    float4 h = hp[k];
    float4 b = ap[k];
    a4.x = fmaf(h.x, b.x, a4.x);
    a4.y = fmaf(h.y, b.y, a4.y);
    a4.z = fmaf(h.z, b.z, a4.z);
    a4.w = fmaf(h.w, b.w, a4.w);
  }
  const float v = ((a4.x + a4.y) + (a4.z + a4.w)) + g;
  const unsigned ov = ordf(v);
  if (ov >= hiw[2 * R + 1]) {  // '>=': let atomicMax resolve smaller-J ties
    const unsigned long long pk =
        ((unsigned long long)ov << 32) | (0xFFFFFFFFu - (unsigned)J);
    atomicMax(&rowslot[R], pk);
  }
}

// ---------------- h = x @ W + b (f64 accumulate) + workspace init ----------
__global__ void k_hraw(const float* __restrict__ x, const float* __restrict__ W,
                       const float* __restrict__ b, float* __restrict__ hraw,
                       unsigned long long* __restrict__ rowslot,
                       float* __restrict__ norms) {
  __shared__ float sx[256];
  const int i = blockIdx.x;
  const int d = threadIdx.x;  // 128 threads
  if (d == 0) {
    rowslot[i] = 0ull;
    if (i == 0) { norms[0] = 0.0f; norms[1] = 0.0f; }
  }
  sx[d] = x[i * 256 + d];
  sx[d + 128] = x[i * 256 + 128 + d];
  __syncthreads();
  double acc = 0.0;
  for (int k = 0; k < 256; ++k)
    acc = fma((double)sx[k], (double)W[k * 128 + d], acc);
  hraw[i * 128 + d] = (float)acc + b[d];
}

// ---------------- BN stats per column (f64) ----------------
__global__ void k_bnstats(const float* __restrict__ hraw,
                          float* __restrict__ meanv, float* __restrict__ rsv) {
  __shared__ double red[256];
  const int d = blockIdx.x;   // 128 blocks
  const int t = threadIdx.x;  // 256 threads
  double s = 0.0;
  for (int i = t; i < 2048; i += 256) s += (double)hraw[i * 128 + d];
  red[t] = s;
  __syncthreads();
  for (int off = 128; off > 0; off >>= 1) {
    if (t < off) red[t] += red[t + off];
    __syncthreads();
  }
  const float m = (float)(red[0] * (1.0 / 2048.0));
  __syncthreads();
  double v = 0.0;
  for (int i = t; i < 2048; i += 256) {
    float dd = __fsub_rn(hraw[i * 128 + d], m);
    v += (double)dd * (double)dd;
  }
  red[t] = v;
  __syncthreads();
  for (int off = 128; off > 0; off >>= 1) {
    if (t < off) red[t] += red[t + off];
    __syncthreads();
  }
  if (t == 0) {
    float var = (float)(red[0] * (1.0 / 2048.0));
    float vpe = __fadd_rn(var, 1e-5f);
    meanv[d] = m;
    rsv[d] = (float)(1.0 / sqrt((double)vpe));
  }
}

// ---------------- apply BN + leaky relu, emit bf16 copy + max row-norm ------
__global__ void k_apply(const float* __restrict__ hraw,
                        const float* __restrict__ meanv, const float* __restrict__ rsv,
                        const float* __restrict__ gamma, const float* __restrict__ beta,
                        float* __restrict__ hfin, unsigned short* __restrict__ hb,
                        float* __restrict__ norms) {
  __shared__ float red[256];
  const int t = threadIdx.x;
  const int idx = blockIdx.x * 256 + t;  // 2 rows per block
  const int d = idx & 127;
  float h = hraw[idx];
  float hn = __fadd_rn(__fmul_rn(__fmul_rn(__fsub_rn(h, meanv[d]), rsv[d]), gamma[d]), beta[d]);
  float o = (hn >= 0.0f) ? hn : __fmul_rn(0.01f, hn);
  hfin[idx] = o;
  hb[idx] = f2bf(o);
  red[t] = o * o;
  __syncthreads();
  for (int off = 64; off > 0; off >>= 1) {
    if ((t & 127) < off) red[t] += red[t + off];
    __syncthreads();
  }
  if ((t & 127) == 0) atomicMax((unsigned*)&norms[0], __float_as_uint(red[t]));
}

// ---------------- max item row-norm^2: one atomic per block ----------------
__global__ void k_anorm(const float* __restrict__ items, float* __restrict__ norms) {
  __shared__ float red[256];
  const int t = threadIdx.x;   // 256: 8 row-groups x 32 lanes
  const int r0 = blockIdx.x * 250;  // grid 200
  float mx = 0.0f;
  for (int rr = (t >> 5); rr < 250; rr += 8) {
    const float4 v = *(const float4*)(items + (size_t)(r0 + rr) * 128 + (t & 31) * 4);
    float ss = v.x * v.x + v.y * v.y + v.z * v.z + v.w * v.w;
    for (int m = 1; m <= 16; m <<= 1) ss += __shfl_xor(ss, m);
    mx = fmaxf(mx, ss);
  }
  red[t] = mx;
  __syncthreads();
  for (int off = 128; off > 0; off >>= 1) {
    if (t < off) red[t] = fmaxf(red[t], red[t + off]);
    __syncthreads();
  }
  if (t == 0) atomicMax((unsigned*)&norms[1], __float_as_uint(red[0]));
}

// ---------------- V0 seed: per-row achieved max over j in [0,1024) ----------
__global__ __launch_bounds__(256, 4) void k_seed(const float* __restrict__ hfin,
                                                 const float* __restrict__ items,
                                                 float* __restrict__ V0) {
  __shared__ float red[4][256];
  const int t = threadIdx.x;
  const int rbase = blockIdx.x * 4;
  float best[4] = {-INFINITY, -INFINITY, -INFINITY, -INFINITY};
  for (int q = 0; q < 4; ++q) {
    const int j = t + 256 * q;
    float acc[4] = {0.0f, 0.0f, 0.0f, 0.0f};
    const float* ap = items + (size_t)j * 128;
    for (int km = 0; km < 8; ++km) {
#pragma unroll
      for (int e = 0; e < 4; ++e) {
        float4 a4 = *(const float4*)(ap + km * 16 + 4 * e);
#pragma unroll
        for (int p = 0; p < 4; ++p) {
          const float* hp = hfin + (rbase + p) * 128 + km * 16 + 4 * e;
          float4 h4 = *(const float4*)hp;  // uniform -> s_load
          acc[p] = fmaf(h4.x, a4.x, acc[p]);
          acc[p] = fmaf(h4.y, a4.y, acc[p]);
          acc[p] = fmaf(h4.z, a4.z, acc[p]);
          acc[p] = fmaf(h4.w, a4.w, acc[p]);
        }
      }
    }
#pragma unroll
    for (int p = 0; p < 4; ++p) {
      unsigned l = (unsigned)(rbase + p) * 50000u + (unsigned)j;
      float g = gumbel_from_bits(tf2x32_xor(0u, l));
      best[p] = fmaxf(best[p], acc[p] + g);
    }
  }
#pragma unroll
  for (int p = 0; p < 4; ++p) red[p][t] = best[p];
  __syncthreads();
  for (int off = 128; off > 0; off >>= 1) {
    if (t < off) {
#pragma unroll
      for (int p = 0; p < 4; ++p) red[p][t] = fmaxf(red[p][t], red[p][t + off]);
    }
    __syncthreads();
  }
  if (t < 4) V0[rbase + t] = red[t][0];
}

// ---------------- bf16 MFMA screen + tiered exact rescore -----------------
// grid (8, 98): block = 256 rows x (JLOOP x 32) j. 512 threads = 8 waves,
// each wave 32 rows x 32 j = 2 row-tiles x 2 j-tiles of 16x16, K=128 via 4
// chained mfma_f32_16x16x32_bf16. 8192 pairs per flush window; ~10% tier-1
// pass rate -> ~800 queued << QCAP=4096 (overflow path correct but rare).
// Tier-1 (screen):  s_bf16 >= tv - GMAX - ERRC   (gumbel unknown yet)
// Tier-2 (flush):   s_bf16 + g >= tv - ERRC      (exact g, bf16 score)
// Tier-3: exact fp32 dot + guarded atomicMax -- in resolve_cand (noinline).
__global__ __launch_bounds__(512, 2) void k_screen(
    const unsigned short* __restrict__ hb, const float* __restrict__ hfin,
    const float* __restrict__ items, const float* __restrict__ V0,
    const float* __restrict__ norms, unsigned long long* __restrict__ rowslot) {
  __shared__ __align__(16) unsigned short Bs[32 * 128];  // 8KB swizzled bf16
  __shared__ unsigned qkey[QCAP];                        // 16KB
  __shared__ float qs[QCAP];                             // 16KB
  __shared__ float thrLds[256];   // tier-1 threshold
  __shared__ float thr2Lds[256];  // tier-2 threshold (= tv - ERRC)
  __shared__ unsigned qcnt;

  const int t = threadIdx.x;
  const int r0 = blockIdx.x * 256;
  const float ERRC = 0.004f * sqrtf(norms[0] * norms[1]) + 0.01f;
  const volatile unsigned* hiw = (const volatile unsigned*)rowslot;  // hi at 2R+1

  const int w = t >> 6, l = t & 63;
  const int lg = l >> 4, lr = l & 15;

  // resident A fragments: lane holds row (r0 + w*32 [+16] + lr), 8 k each
  const unsigned short* aB0 = hb + (size_t)(r0 + w * 32 + lr) * 128 + lg * 8;
  bf16x8 Afrag[2][4];
#pragma unroll
  for (int kb = 0; kb < 4; ++kb) {
    Afrag[0][kb] = *(const bf16x8*)(aB0 + kb * 32);
    Afrag[1][kb] = *(const bf16x8*)(aB0 + 16 * 128 + kb * 32);
  }

  for (int it = 0; it < JLOOP; ++it) {
    const int j0 = (blockIdx.y * JLOOP + it) * 32;
    if (j0 >= 50000) break;

    __syncthreads();  // prev iter's Bs/queue consumers done
    if (t == 0) qcnt = 0;

    // ---- stage B tile: 32 rows of items, fp32 -> bf16 LDS, XOR-swizzled --
    {
      const int jl = t >> 4;            // 0..31
      const int c0 = (t & 15) * 8;      // float col base (8 floats = 16B bf16)
      const int Jg = min(j0 + jl, 49999);
      const float4* src = (const float4*)(items + (size_t)Jg * 128 + c0);
      float4 f0 = src[0], f1 = src[1];
      uint4 A;
      A.x = pk2(f0.x, f0.y); A.y = pk2(f0.z, f0.w);
      A.z = pk2(f1.x, f1.y); A.w = pk2(f1.z, f1.w);
      *(uint4*)((char*)Bs + bswz(jl * 256 + c0 * 2)) = A;
    }
    // ---- per-row dynamic thresholds (plain load, stale-low is safe) ----
    if (t < 256) {
      const int R = r0 + t;
      const unsigned hi = hiw[2 * R + 1];
      float tv = V0[R];
      if (hi) tv = fmaxf(tv, unordf(hi));
      thrLds[t] = tv - GMAX - ERRC;
      thr2Lds[t] = tv - ERRC;
    }
    __syncthreads();

    f32x4 acc[2][2];
#pragma unroll
    for (int rt = 0; rt < 2; ++rt)
#pragma unroll
      for (int jt = 0; jt < 2; ++jt) acc[rt][jt] = (f32x4){0.f, 0.f, 0.f, 0.f};

#pragma unroll
    for (int kb = 0; kb < 4; ++kb) {
#pragma unroll
      for (int jt = 0; jt < 2; ++jt) {
        const int byte = (jt * 16 + lr) * 256 + kb * 64 + lg * 16;
        bf16x8 bfrag = *(const bf16x8*)((char*)Bs + bswz(byte));
        acc[0][jt] = __builtin_amdgcn_mfma_f32_16x16x32_bf16(Afrag[0][kb], bfrag, acc[0][jt], 0, 0, 0);
        acc[1][jt] = __builtin_amdgcn_mfma_f32_16x16x32_bf16(Afrag[1][kb], bfrag, acc[1][jt], 0, 0, 0);
      }
    }

    // ---- tier-1 push (C/D: col = lane&15, row = (lane>>4)*4 + reg) ----
#pragma unroll
    for (int rt = 0; rt < 2; ++rt)
#pragma unroll
      for (int jt = 0; jt < 2; ++jt)
#pragma unroll
        for (int q = 0; q < 4; ++q) {
          const float s = acc[rt][jt][q];
          const int Rl = w * 32 + rt * 16 + lg * 4 + q;  // local row
          const int J = j0 + jt * 16 + lr;
          if (J < 50000 && s >= thrLds[Rl]) {
            const unsigned slot = atomicAdd(&qcnt, 1u);
            if (slot < QCAP) {
              qkey[slot] = ((unsigned)Rl << 16) | (unsigned)J;
              qs[slot] = s;
            } else {
              resolve_cand(r0 + Rl, J, s, thr2Lds[Rl], hfin, items, rowslot, hiw);
            }
          }
        }
    __syncthreads();

    // ---- flush: one candidate per lane ----
    const unsigned n = (qcnt < QCAP) ? qcnt : QCAP;
    for (unsigned i = t; i < n; i += 512) {
      const unsigned key = qkey[i];
      const int Rl = key >> 16;
      const int J = key & 0xFFFFu;
      resolve_cand(r0 + Rl, J, qs[i], thr2Lds[Rl], hfin, items, rowslot, hiw);
    }
  }
}

// ---------------- final: read row winner + cosine sim (one wave/row) -------
__global__ void k_final(const unsigned long long* __restrict__ rowslot,
                        const int* __restrict__ uid, const float* __restrict__ items,
                        float* __restrict__ dout, float* __restrict__ simv) {
  const int r = blockIdx.x;
  const int lane = threadIdx.x;  // 64
  const unsigned long long pk = rowslot[r];  // nonzero: winner always pushed
  const int bi = (int)(0xFFFFFFFFu - (unsigned)pk);
  if (lane == 0) dout[r] = (float)bi;

  const int orig = uid[r * 2 + 1];
  float o1 = items[(size_t)orig * 128 + lane];
  float o2 = items[(size_t)orig * 128 + 64 + lane];
  float p1 = items[(size_t)bi * 128 + lane];
  float p2 = items[(size_t)bi * 128 + 64 + lane];
  float d = o1 * p1 + o2 * p2;
  float s1 = o1 * o1 + o2 * o2;
  float s2 = p1 * p1 + p2 * p2;
  for (int off = 32; off > 0; off >>= 1) {
    d += __shfl_down(d, off);
    s1 += __shfl_down(s1, off);
    s2 += __shfl_down(s2, off);
  }
  if (lane == 0) {
    float n1 = fmaxf(sqrtf(s1), 1e-6f);
    float n2 = fmaxf(sqrtf(s2), 1e-6f);
    float sim = d / (n1 * n2);
    simv[r] = (sim + 1.0f) * 0.5f;
  }
}

// ---------------- final scalar reductions ----------------
__global__ void k_reduce(const float* __restrict__ simv, float* __restrict__ dout) {
  __shared__ double rl[256];
  __shared__ double rs[256];
  const int t = threadIdx.x;
  double L = 0.0, S = 0.0;
  for (int i = t; i < 2048; i += 256) {
    double s = (double)simv[i];
    double dd = s - 0.5;
    L += dd * dd;
    S += s;
  }
  rl[t] = L; rs[t] = S;
  __syncthreads();
  for (int off = 128; off > 0; off >>= 1) {
    if (t < off) { rl[t] += rl[t + off]; rs[t] += rs[t + off]; }
    __syncthreads();
  }
  if (t == 0) {
    dout[2048] = (float)(rl[0] * (1.0 / 2048.0));
    dout[2049] = (float)(rs[0] * (1.0 / 2048.0));
  }
}

extern "C" void kernel_launch(void* const* d_in, const int* in_sizes, int n_in,
                              void* d_out, int out_size, void* d_ws, size_t ws_size,
                              hipStream_t stream) {
  const int* uid = (const int*)d_in[0];       // (2048,2) int32
  const float* xfeat = (const float*)d_in[1]; // (2048,256)
  const float* items = (const float*)d_in[2]; // (50000,128)
  const float* W = (const float*)d_in[3];     // (256,128)
  const float* bias = (const float*)d_in[4];  // (128,)
  const float* gamma = (const float*)d_in[5]; // (128,)
  const float* beta = (const float*)d_in[6];  // (128,)

  float* ws = (float*)d_ws;
  float* hraw = ws;                                   // 262144 f
  float* hfin = ws + 262144;                          // 262144 f
  float* meanv = ws + 524288;                         // 128 f
  float* rsv = ws + 524416;                           // 128 f
  float* V0 = ws + 524544;                            // 2048 f
  float* simv = ws + 526592;                          // 2048 f
  float* norms = ws + 528640;                         // 2 f (Hmax^2, Amax^2)
  unsigned long long* rowslot =
      (unsigned long long*)(ws + 528642);             // 2048 u64 (8B aligned)
  unsigned short* hb = (unsigned short*)(ws + 532740); // 262144 bf16 (16B aligned)
  float* dout = (float*)d_out;                        // 2050 floats

  hipLaunchKernelGGL(k_hraw, dim3(2048), dim3(128), 0, stream, xfeat, W, bias, hraw, rowslot, norms);
  hipLaunchKernelGGL(k_bnstats, dim3(128), dim3(256), 0, stream, hraw, meanv, rsv);
  hipLaunchKernelGGL(k_apply, dim3(1024), dim3(256), 0, stream, hraw, meanv, rsv, gamma, beta, hfin, hb, norms);
  hipLaunchKernelGGL(k_anorm, dim3(200), dim3(256), 0, stream, items, norms);
  hipLaunchKernelGGL(k_seed, dim3(512), dim3(256), 0, stream, hfin, items, V0);
  hipLaunchKernelGGL(k_screen, dim3(8, 98), dim3(512), 0, stream, hb, hfin, items, V0, norms, rowslot);
  hipLaunchKernelGGL(k_final, dim3(2048), dim3(64), 0, stream, rowslot, uid, items, dout, simv);
  hipLaunchKernelGGL(k_reduce, dim3(1), dim3(256), 0, stream, simv, dout);
}

// Round 6
// 433.950 us; speedup vs baseline: 2.8937x; 1.0728x over previous
//
#include <hip/hip_runtime.h>
#include <math.h>

#define TINYF 1.17549435e-38f
#define GMAX 16.0f   // hard upper bound on gumbel (15.9424) + slack
#define QCAP 2048    // per ping-pong buffer
#define NTILES 1563  // ceil(50000/32)
#define TPB 25       // tiles per block (64 spans x 25 >= 1563)

typedef __attribute__((ext_vector_type(8))) short bf16x8;
typedef __attribute__((ext_vector_type(4))) float f32x4;

// ---------------- threefry2x32, key = (0, 42) ----------------
__device__ __forceinline__ unsigned rotl32(unsigned x, int r) {
  return (x << r) | (x >> (32 - r));
}

__device__ __forceinline__ unsigned tf2x32_xor(unsigned x0, unsigned x1) {
  const unsigned k0 = 0u, k1 = 42u, k2 = 0x1BD11BF0u;  // 0x1BD11BDA ^ 0 ^ 42
  x0 += k0; x1 += k1;
#define TFR(r) { x0 += x1; x1 = rotl32(x1, r); x1 ^= x0; }
  TFR(13) TFR(15) TFR(26) TFR(6)
  x0 += k1; x1 += k2 + 1u;
  TFR(17) TFR(29) TFR(16) TFR(24)
  x0 += k2; x1 += k0 + 2u;
  TFR(13) TFR(15) TFR(26) TFR(6)
  x0 += k0; x1 += k1 + 3u;
  TFR(17) TFR(29) TFR(16) TFR(24)
  x0 += k1; x1 += k2 + 4u;
  TFR(13) TFR(15) TFR(26) TFR(6)
  x0 += k2; x1 += k0 + 5u;
#undef TFR
  return x0 ^ x1;
}

__device__ __forceinline__ float gumbel_from_bits(unsigned bits) {
  float f = __uint_as_float((bits >> 9) | 0x3f800000u) - 1.0f;
  float u = fmaxf(f, TINYF);
  return -logf(-logf(u));
}

// order-preserving float->uint (monotone)
__device__ __forceinline__ unsigned ordf(float v) {
  unsigned b = __float_as_uint(v);
  return (b & 0x80000000u) ? ~b : (b | 0x80000000u);
}
__device__ __forceinline__ float unordf(unsigned u) {
  unsigned b = (u & 0x80000000u) ? (u & 0x7FFFFFFFu) : ~u;
  return __uint_as_float(b);
}

// fp32 -> bf16 RNE (bit trick)
__device__ __forceinline__ unsigned short f2bf(float f) {
  unsigned u = __float_as_uint(f);
  unsigned r = u + 0x7FFFu + ((u >> 16) & 1u);
  return (unsigned short)(r >> 16);
}
__device__ __forceinline__ unsigned pk2(float a, float b) {
  return (unsigned)f2bf(a) | ((unsigned)f2bf(b) << 16);
}
// LDS XOR swizzle for 256B-row tile (breaks 32-way ds_read_b128 conflict)
__device__ __forceinline__ int bswz(int b) { return b ^ (((b >> 8) & 7) << 4); }

// ---- candidate resolution: gumbel, tier-2 test, exact fp32 dot, atomicMax.
// ONE copy (noinline) -- shared by queue flush and overflow path.
__device__ __attribute__((noinline)) void resolve_cand(
    int R, int J, float s, float thr2,
    const float* __restrict__ hfin, const float* __restrict__ items,
    unsigned long long* __restrict__ rowslot, const volatile unsigned* hiw) {
  const unsigned lc = (unsigned)R * 50000u + (unsigned)J;
  const float g = gumbel_from_bits(tf2x32_xor(0u, lc));
  if (s + g < thr2) return;  // sound: s_fp32 + g <= s_bf16 + ERRC + g
  const float4* hp = (const float4*)(hfin + (size_t)R * 128);
  const float4* ap = (const float4*)(items + (size_t)J * 128);
  float4 a4 = {0.f, 0.f, 0.f, 0.f};
#pragma unroll
  for (int k = 0; k < 32; ++k) {
    float4 h = hp[k];
    float4 b = ap[k];
    a4.x = fmaf(h.x, b.x, a4.x);
    a4.y = fmaf(h.y, b.y, a4.y);
    a4.z = fmaf(h.z, b.z, a4.z);
    a4.w = fmaf(h.w, b.w, a4.w);
  }
  const float v = ((a4.x + a4.y) + (a4.z + a4.w)) + g;
  const unsigned ov = ordf(v);
  if (ov >= hiw[2 * R + 1]) {  // '>=': let atomicMax resolve smaller-J ties
    const unsigned long long pk =
        ((unsigned long long)ov << 32) | (0xFFFFFFFFu - (unsigned)J);
    atomicMax(&rowslot[R], pk);
  }
}

// ---------------- h = x @ W + b (f64 accumulate) + workspace init ----------
__global__ void k_hraw(const float* __restrict__ x, const float* __restrict__ W,
                       const float* __restrict__ b, float* __restrict__ hraw,
                       unsigned long long* __restrict__ rowslot,
                       float* __restrict__ norms) {
  __shared__ float sx[256];
  const int i = blockIdx.x;
  const int d = threadIdx.x;  // 128 threads
  if (d == 0) {
    rowslot[i] = 0ull;
    if (i == 0) { norms[0] = 0.0f; norms[1] = 0.0f; }
  }
  sx[d] = x[i * 256 + d];
  sx[d + 128] = x[i * 256 + 128 + d];
  __syncthreads();
  double acc = 0.0;
  for (int k = 0; k < 256; ++k)
    acc = fma((double)sx[k], (double)W[k * 128 + d], acc);
  hraw[i * 128 + d] = (float)acc + b[d];
}

// ---------------- BN stats per column (f64) ----------------
__global__ void k_bnstats(const float* __restrict__ hraw,
                          float* __restrict__ meanv, float* __restrict__ rsv) {
  __shared__ double red[256];
  const int d = blockIdx.x;   // 128 blocks
  const int t = threadIdx.x;  // 256 threads
  double s = 0.0;
  for (int i = t; i < 2048; i += 256) s += (double)hraw[i * 128 + d];
  red[t] = s;
  __syncthreads();
  for (int off = 128; off > 0; off >>= 1) {
    if (t < off) red[t] += red[t + off];
    __syncthreads();
  }
  const float m = (float)(red[0] * (1.0 / 2048.0));
  __syncthreads();
  double v = 0.0;
  for (int i = t; i < 2048; i += 256) {
    float dd = __fsub_rn(hraw[i * 128 + d], m);
    v += (double)dd * (double)dd;
  }
  red[t] = v;
  __syncthreads();
  for (int off = 128; off > 0; off >>= 1) {
    if (t < off) red[t] += red[t + off];
    __syncthreads();
  }
  if (t == 0) {
    float var = (float)(red[0] * (1.0 / 2048.0));
    float vpe = __fadd_rn(var, 1e-5f);
    meanv[d] = m;
    rsv[d] = (float)(1.0 / sqrt((double)vpe));
  }
}

// ---------------- apply BN + leaky relu, emit bf16 copy + max row-norm ------
__global__ void k_apply(const float* __restrict__ hraw,
                        const float* __restrict__ meanv, const float* __restrict__ rsv,
                        const float* __restrict__ gamma, const float* __restrict__ beta,
                        float* __restrict__ hfin, unsigned short* __restrict__ hb,
                        float* __restrict__ norms) {
  __shared__ float red[256];
  const int t = threadIdx.x;
  const int idx = blockIdx.x * 256 + t;  // 2 rows per block
  const int d = idx & 127;
  float h = hraw[idx];
  float hn = __fadd_rn(__fmul_rn(__fmul_rn(__fsub_rn(h, meanv[d]), rsv[d]), gamma[d]), beta[d]);
  float o = (hn >= 0.0f) ? hn : __fmul_rn(0.01f, hn);
  hfin[idx] = o;
  hb[idx] = f2bf(o);
  red[t] = o * o;
  __syncthreads();
  for (int off = 64; off > 0; off >>= 1) {
    if ((t & 127) < off) red[t] += red[t + off];
    __syncthreads();
  }
  if ((t & 127) == 0) atomicMax((unsigned*)&norms[0], __float_as_uint(red[t]));
}

// ---------------- max item row-norm^2: 32 rows/block, 1 atomic/block -------
__global__ void k_anorm(const float* __restrict__ items, float* __restrict__ norms) {
  __shared__ float red[4];
  const int t = threadIdx.x;  // 256: 32 rows x 8 lanes
  int row = blockIdx.x * 32 + (t >> 3);  // grid 1563
  if (row > 49999) row = 49999;          // dup row: harmless for max
  const float4* p = (const float4*)(items + (size_t)row * 128 + (t & 7) * 16);
  float ss = 0.0f;
#pragma unroll
  for (int k = 0; k < 4; ++k) {
    float4 v = p[k];
    ss += v.x * v.x + v.y * v.y + v.z * v.z + v.w * v.w;
  }
  ss += __shfl_xor(ss, 1);  // sum 8-lane row group
  ss += __shfl_xor(ss, 2);
  ss += __shfl_xor(ss, 4);
  ss = fmaxf(ss, __shfl_xor(ss, 8));   // max across rows in wave
  ss = fmaxf(ss, __shfl_xor(ss, 16));
  ss = fmaxf(ss, __shfl_xor(ss, 32));
  if ((t & 63) == 0) red[t >> 6] = ss;
  __syncthreads();
  if (t == 0) {
    float mx = fmaxf(fmaxf(red[0], red[1]), fmaxf(red[2], red[3]));
    atomicMax((unsigned*)&norms[1], __float_as_uint(mx));
  }
}

// ---------------- V0 seed: per-row achieved max over j in [0,1024) ----------
__global__ __launch_bounds__(256, 4) void k_seed(const float* __restrict__ hfin,
                                                 const float* __restrict__ items,
                                                 float* __restrict__ V0) {
  __shared__ float red[4][256];
  const int t = threadIdx.x;
  const int rbase = blockIdx.x * 4;
  float best[4] = {-INFINITY, -INFINITY, -INFINITY, -INFINITY};
  for (int q = 0; q < 4; ++q) {
    const int j = t + 256 * q;
    float acc[4] = {0.0f, 0.0f, 0.0f, 0.0f};
    const float* ap = items + (size_t)j * 128;
    for (int km = 0; km < 8; ++km) {
#pragma unroll
      for (int e = 0; e < 4; ++e) {
        float4 a4 = *(const float4*)(ap + km * 16 + 4 * e);
#pragma unroll
        for (int p = 0; p < 4; ++p) {
          const float* hp = hfin + (rbase + p) * 128 + km * 16 + 4 * e;
          float4 h4 = *(const float4*)hp;  // uniform -> s_load
          acc[p] = fmaf(h4.x, a4.x, acc[p]);
          acc[p] = fmaf(h4.y, a4.y, acc[p]);
          acc[p] = fmaf(h4.z, a4.z, acc[p]);
          acc[p] = fmaf(h4.w, a4.w, acc[p]);
        }
      }
    }
#pragma unroll
    for (int p = 0; p < 4; ++p) {
      unsigned l = (unsigned)(rbase + p) * 50000u + (unsigned)j;
      float g = gumbel_from_bits(tf2x32_xor(0u, l));
      best[p] = fmaxf(best[p], acc[p] + g);
    }
  }
#pragma unroll
  for (int p = 0; p < 4; ++p) red[p][t] = best[p];
  __syncthreads();
  for (int off = 128; off > 0; off >>= 1) {
    if (t < off) {
#pragma unroll
      for (int p = 0; p < 4; ++p) red[p][t] = fmaxf(red[p][t], red[p][t + off]);
    }
    __syncthreads();
  }
  if (t < 4) V0[rbase + t] = red[t][0];
}

// ---------------- bf16 MFMA screen: pipelined + ping-pong queue ------------
// grid 512 (1-D): rg = bid>>6 (8 row-groups of 256), by = bid&63 (j-span).
// bid%8 == by%8 -> all 8 row-groups of one span land on ONE XCD's L2: the
// items tile is fetched once per span, not 8x.
// Pipeline per iter (2 barriers): convert prefetched regs -> Bs; reset
// qc[pb]; thresholds | barrier A | issue prefetch(it+1) -> regs; MFMA+push
// into queue[pb] | barrier B | flush queue[pb]. Load latency of tile it+1
// hides under MFMA+push+flush. Queue ping-pong removes the 3rd barrier
// (flush(it) reads buf pb while it+1 resets/pushes buf pb^1). Threshold-LDS
// overwrite during flush is sound: thresholds only tighten (monotone) and
// any thr <= running_max - ERRC never rejects the true winner.
__global__ __launch_bounds__(512, 2) void k_screen(
    const unsigned short* __restrict__ hb, const float* __restrict__ hfin,
    const float* __restrict__ items, const float* __restrict__ V0,
    const float* __restrict__ norms, unsigned long long* __restrict__ rowslot) {
  __shared__ __align__(16) unsigned short Bs[32 * 128];  // 8KB swizzled bf16
  __shared__ unsigned qkey[2][QCAP];                     // 16KB
  __shared__ float qs[2][QCAP];                          // 16KB
  __shared__ float thrLds[256];   // tier-1 threshold
  __shared__ float thr2Lds[256];  // tier-2 threshold (= tv - ERRC)
  __shared__ unsigned qc[2];

  const int t = threadIdx.x;
  const int rg = blockIdx.x >> 6;
  const int by = blockIdx.x & 63;
  const int r0 = rg * 256;
  int nt = NTILES - by * TPB;
  nt = nt < 0 ? 0 : (nt > TPB ? TPB : nt);
  if (nt == 0) return;  // block-uniform
  const int tile0 = by * TPB;

  const float ERRC = 0.004f * sqrtf(norms[0] * norms[1]) + 0.01f;
  const volatile unsigned* hiw = (const volatile unsigned*)rowslot;  // hi @ 2R+1

  const int w = t >> 6, l = t & 63;
  const int lg = l >> 4, lr = l & 15;

  // resident A fragments: lane holds row (r0 + w*32 [+16] + lr), 8 k each
  const unsigned short* aB0 = hb + (size_t)(r0 + w * 32 + lr) * 128 + lg * 8;
  bf16x8 Afrag[2][4];
#pragma unroll
  for (int kb = 0; kb < 4; ++kb) {
    Afrag[0][kb] = *(const bf16x8*)(aB0 + kb * 32);
    Afrag[1][kb] = *(const bf16x8*)(aB0 + 16 * 128 + kb * 32);
  }

  // staging geometry: 512 threads cover 32 rows x 128 cols fp32
  const int jl = t >> 4;          // 0..31 tile row
  const int c0 = (t & 15) * 8;    // float col base (16B of bf16)

  // prologue: prefetch tile0 into regs
  float4 f0, f1;
  {
    const int Jg = min(tile0 * 32 + jl, 49999);
    const float4* src = (const float4*)(items + (size_t)Jg * 128 + c0);
    f0 = src[0]; f1 = src[1];
  }

  int pb = 0;
  for (int it = 0; it < nt; ++it) {
    const int j0 = (tile0 + it) * 32;

    // ---- convert prefetched regs -> swizzled LDS ----
    {
      uint4 A;
      A.x = pk2(f0.x, f0.y); A.y = pk2(f0.z, f0.w);
      A.z = pk2(f1.x, f1.y); A.w = pk2(f1.z, f1.w);
      *(uint4*)((char*)Bs + bswz(jl * 256 + c0 * 2)) = A;
    }
    if (t == 0) qc[pb] = 0;
    // ---- per-row dynamic thresholds (plain load, stale-low is safe) ----
    if (t < 256) {
      const int R = r0 + t;
      const unsigned hi = hiw[2 * R + 1];
      float tv = V0[R];
      if (hi) tv = fmaxf(tv, unordf(hi));
      thrLds[t] = tv - GMAX - ERRC;
      thr2Lds[t] = tv - ERRC;
    }
    __syncthreads();  // A: Bs + thresholds + qc[pb] ready

    // ---- issue prefetch for tile it+1 (hides under MFMA+push+flush) ----
    if (it + 1 < nt) {
      const int Jg = min((tile0 + it + 1) * 32 + jl, 49999);
      const float4* src = (const float4*)(items + (size_t)Jg * 128 + c0);
      f0 = src[0]; f1 = src[1];
    }

    // ---- MFMA ----
    f32x4 acc[2][2];
#pragma unroll
    for (int rt = 0; rt < 2; ++rt)
#pragma unroll
      for (int jt = 0; jt < 2; ++jt) acc[rt][jt] = (f32x4){0.f, 0.f, 0.f, 0.f};

#pragma unroll
    for (int kb = 0; kb < 4; ++kb) {
#pragma unroll
      for (int jt = 0; jt < 2; ++jt) {
        const int byte = (jt * 16 + lr) * 256 + kb * 64 + lg * 16;
        bf16x8 bfrag = *(const bf16x8*)((char*)Bs + bswz(byte));
        acc[0][jt] = __builtin_amdgcn_mfma_f32_16x16x32_bf16(Afrag[0][kb], bfrag, acc[0][jt], 0, 0, 0);
        acc[1][jt] = __builtin_amdgcn_mfma_f32_16x16x32_bf16(Afrag[1][kb], bfrag, acc[1][jt], 0, 0, 0);
      }
    }

    // ---- tier-1 push (C/D: col = lane&15, row = (lane>>4)*4 + reg) ----
#pragma unroll
    for (int rt = 0; rt < 2; ++rt)
#pragma unroll
      for (int jt = 0; jt < 2; ++jt)
#pragma unroll
        for (int q = 0; q < 4; ++q) {
          const float s = acc[rt][jt][q];
          const int Rl = w * 32 + rt * 16 + lg * 4 + q;  // local row
          const int J = j0 + jt * 16 + lr;
          if (J < 50000 && s >= thrLds[Rl]) {
            const unsigned slot = atomicAdd(&qc[pb], 1u);
            if (slot < QCAP) {
              qkey[pb][slot] = ((unsigned)Rl << 16) | (unsigned)J;
              qs[pb][slot] = s;
            } else {  // overflow: resolve inline (correct, rare)
              resolve_cand(r0 + Rl, J, s, thr2Lds[Rl], hfin, items, rowslot, hiw);
            }
          }
        }
    __syncthreads();  // B: queue[pb] final

    // ---- flush queue[pb]: one candidate per lane ----
    const unsigned n = (qc[pb] < QCAP) ? qc[pb] : QCAP;
    for (unsigned i = t; i < n; i += 512) {
      const unsigned key = qkey[pb][i];
      const int Rl = key >> 16;
      const int J = key & 0xFFFFu;
      resolve_cand(r0 + Rl, J, qs[pb][i], thr2Lds[Rl], hfin, items, rowslot, hiw);
    }
    pb ^= 1;
  }
}

// ---------------- final: read row winner + cosine sim (one wave/row) -------
__global__ void k_final(const unsigned long long* __restrict__ rowslot,
                        const int* __restrict__ uid, const float* __restrict__ items,
                        float* __restrict__ dout, float* __restrict__ simv) {
  const int r = blockIdx.x;
  const int lane = threadIdx.x;  // 64
  const unsigned long long pk = rowslot[r];  // nonzero: winner always pushed
  const int bi = (int)(0xFFFFFFFFu - (unsigned)pk);
  if (lane == 0) dout[r] = (float)bi;

  const int orig = uid[r * 2 + 1];
  float o1 = items[(size_t)orig * 128 + lane];
  float o2 = items[(size_t)orig * 128 + 64 + lane];
  float p1 = items[(size_t)bi * 128 + lane];
  float p2 = items[(size_t)bi * 128 + 64 + lane];
  float d = o1 * p1 + o2 * p2;
  float s1 = o1 * o1 + o2 * o2;
  float s2 = p1 * p1 + p2 * p2;
  for (int off = 32; off > 0; off >>= 1) {
    d += __shfl_down(d, off);
    s1 += __shfl_down(s1, off);
    s2 += __shfl_down(s2, off);
  }
  if (lane == 0) {
    float n1 = fmaxf(sqrtf(s1), 1e-6f);
    float n2 = fmaxf(sqrtf(s2), 1e-6f);
    float sim = d / (n1 * n2);
    simv[r] = (sim + 1.0f) * 0.5f;
  }
}

// ---------------- final scalar reductions ----------------
__global__ void k_reduce(const float* __restrict__ simv, float* __restrict__ dout) {
  __shared__ double rl[256];
  __shared__ double rs[256];
  const int t = threadIdx.x;
  double L = 0.0, S = 0.0;
  for (int i = t; i < 2048; i += 256) {
    double s = (double)simv[i];
    double dd = s - 0.5;
    L += dd * dd;
    S += s;
  }
  rl[t] = L; rs[t] = S;
  __syncthreads();
  for (int off = 128; off > 0; off >>= 1) {
    if (t < off) { rl[t] += rl[t + off]; rs[t] += rs[t + off]; }
    __syncthreads();
  }
  if (t == 0) {
    dout[2048] = (float)(rl[0] * (1.0 / 2048.0));
    dout[2049] = (float)(rs[0] * (1.0 / 2048.0));
  }
}

extern "C" void kernel_launch(void* const* d_in, const int* in_sizes, int n_in,
                              void* d_out, int out_size, void* d_ws, size_t ws_size,
                              hipStream_t stream) {
  const int* uid = (const int*)d_in[0];       // (2048,2) int32
  const float* xfeat = (const float*)d_in[1]; // (2048,256)
  const float* items = (const float*)d_in[2]; // (50000,128)
  const float* W = (const float*)d_in[3];     // (256,128)
  const float* bias = (const float*)d_in[4];  // (128,)
  const float* gamma = (const float*)d_in[5]; // (128,)
  const float* beta = (const float*)d_in[6];  // (128,)

  float* ws = (float*)d_ws;
  float* hraw = ws;                                   // 262144 f
  float* hfin = ws + 262144;                          // 262144 f
  float* meanv = ws + 524288;                         // 128 f
  float* rsv = ws + 524416;                           // 128 f
  float* V0 = ws + 524544;                            // 2048 f
  float* simv = ws + 526592;                          // 2048 f
  float* norms = ws + 528640;                         // 2 f (Hmax^2, Amax^2)
  unsigned long long* rowslot =
      (unsigned long long*)(ws + 528642);             // 2048 u64 (8B aligned)
  unsigned short* hb = (unsigned short*)(ws + 532740); // 262144 bf16 (16B aligned)
  float* dout = (float*)d_out;                        // 2050 floats

  hipLaunchKernelGGL(k_hraw, dim3(2048), dim3(128), 0, stream, xfeat, W, bias, hraw, rowslot, norms);
  hipLaunchKernelGGL(k_bnstats, dim3(128), dim3(256), 0, stream, hraw, meanv, rsv);
  hipLaunchKernelGGL(k_apply, dim3(1024), dim3(256), 0, stream, hraw, meanv, rsv, gamma, beta, hfin, hb, norms);
  hipLaunchKernelGGL(k_anorm, dim3(1563), dim3(256), 0, stream, items, norms);
  hipLaunchKernelGGL(k_seed, dim3(512), dim3(256), 0, stream, hfin, items, V0);
  hipLaunchKernelGGL(k_screen, dim3(512), dim3(512), 0, stream, hb, hfin, items, V0, norms, rowslot);
  hipLaunchKernelGGL(k_final, dim3(2048), dim3(64), 0, stream, rowslot, uid, items, dout, simv);
  hipLaunchKernelGGL(k_reduce, dim3(1), dim3(256), 0, stream, simv, dout);
}